// Round 4
// baseline (18631.285 us; speedup 1.0000x reference)
//
#include <hip/hip_runtime.h>
#include <hip/hip_bf16.h>
#include <hip/hip_cooperative_groups.h>

namespace cg = cooperative_groups;

#define EPSF 1e-15f

typedef __hip_bfloat16 bf16;
typedef __attribute__((ext_vector_type(8))) short short8;
typedef __attribute__((ext_vector_type(4))) float f32x4;

#define F4E(v,i) ((i)==0?(v).x:((i)==1?(v).y:((i)==2?(v).z:(v).w)))
#define U4E(v,i) ((i)==0?(v).x:((i)==1?(v).y:((i)==2?(v).z:(v).w)))

// ---------- helpers ----------
__device__ __forceinline__ float artanh_c(float x) {
  x = fminf(fmaxf(x, -1.f + 1e-5f), 1.f - 1e-5f);
  return 0.5f * log1pf(2.f * x / (1.f - x));
}
__device__ __forceinline__ float sigmoidf(float x) { return 1.f / (1.f + expf(-x)); }
__device__ __forceinline__ float wave_sum(float x) {
#pragma unroll
  for (int o = 32; o > 0; o >>= 1) x += __shfl_xor(x, o);
  return x;
}
__device__ __forceinline__ float bu2f(ushort u) { return __uint_as_float(((unsigned)u) << 16); }
__device__ __forceinline__ ushort f2bu(float v) {
  bf16 t = __float2bfloat16(v);
  union { bf16 b; ushort u; } c; c.b = t; return c.u;
}
__device__ __forceinline__ void split2(float v, ushort& h, ushort& l) {
  h = f2bu(v); l = f2bu(v - bu2f(h));
}

// ---------- weight split-bf16 packing (once per call) ----------
// W0 per GRU (917504): Whz[512x512] Whr[512x512] Uxz[512x256] Uxr[512x256] Uxh[512x256]  ([col][k])
// W1 per GRU (262144): W_hh_[512x512] ; W2 per matrix (131072): wp[256x512]
__global__ __launch_bounds__(256) void k_wconv(
    const float* __restrict__ w_ih_src, const float* __restrict__ w_hh_src,
    const float* __restrict__ w_ih_tgt, const float* __restrict__ w_hh_tgt,
    const float* __restrict__ wp_src, const float* __restrict__ wp_tgt,
    bf16* __restrict__ W0h, bf16* __restrict__ W0l,
    bf16* __restrict__ W1h, bf16* __restrict__ W1l,
    bf16* __restrict__ W2h, bf16* __restrict__ W2l)
{
  const int idx = blockIdx.x * 256 + threadIdx.x;   // 2621440 total
  float v; bf16 *ph, *pl; int oi;
  if (idx < 1835008) {
    const int g = idx / 917504, r = idx % 917504;
    const float* wih = g ? w_ih_tgt : w_ih_src;
    const float* whh = g ? w_hh_tgt : w_hh_src;
    if (r < 262144)      v = whh[524288 + r];             // Whz = w_hh[2]
    else if (r < 524288) v = whh[r - 262144];             // Whr = w_hh[0]
    else if (r < 655360) v = wih[262144 + (r - 524288)];  // Uxz = w_ih[2]
    else if (r < 786432) v = wih[r - 655360];             // Uxr = w_ih[0]
    else                 v = wih[131072 + (r - 786432)];  // Uxh = w_ih[1]
    ph = W0h; pl = W0l; oi = idx;
  } else if (idx < 2359296) {
    const int j = idx - 1835008;
    const int g = j >> 18, r = j & 262143;
    v = (g ? w_hh_tgt : w_hh_src)[262144 + r];            // W_hh_ = w_hh[1]
    ph = W1h; pl = W1l; oi = j;
  } else {
    const int p = idx - 2359296;
    if (p >= 262144) return;
    const int g = p >> 17, r = p & 131071;
    v = (g ? wp_tgt : wp_src)[r];
    ph = W2h; pl = W2l; oi = p;
  }
  ushort hh, ll; split2(v, hh, ll);
  ((ushort*)ph)[oi] = hh; ((ushort*)pl)[oi] = ll;
}

// ---------- token prologue: per (gru,b,s) expmap0 norm factors ----------
__global__ __launch_bounds__(256) void k_tok(
    const float* __restrict__ emb, const int* __restrict__ src_t,
    const int* __restrict__ tgt_t, float4* __restrict__ tokf)
{
  const int item = blockIdx.x * 4 + (threadIdx.x >> 6);
  const int lane = threadIdx.x & 63;
  const int g = item / 51200;
  const int rem = item - g * 51200;
  const int b = rem / 100, s = rem - b * 100;
  const int tok = (g ? tgt_t : src_t)[b * 100 + s];
  const float4 v = ((const float4*)(emb + (size_t)tok * 256))[lane];
  float ss = v.x*v.x + v.y*v.y + v.z*v.z + v.w*v.w;
#pragma unroll
  for (int o = 32; o > 0; o >>= 1) ss += __shfl_xor(ss, o);
  if (lane == 0) {
    const float un = sqrtf(fmaxf(ss, EPSF));
    const float fac = tanhf(un) / un;
    const float xn = sqrtf(fmaxf(fac * fac * ss, EPSF));
    tokf[item] = make_float4(fac, xn, artanh_c(xn), un);
  }
}

// ---------- fill x planes for step 0 ----------
__global__ __launch_bounds__(256) void kx0(
    const float* __restrict__ emb, const int* __restrict__ src_t,
    const int* __restrict__ tgt_t, const float4* __restrict__ tokf,
    bf16* __restrict__ Xh, bf16* __restrict__ Xl)
{
  const int row = blockIdx.x;            // 0..1023
  const int t = threadIdx.x;             // 0..255
  const int g = row >> 9, b = row & 511;
  const int tok = (g ? tgt_t : src_t)[b * 100];
  const float fac = tokf[(g * 512 + b) * 100].x;
  ushort hh, ll; split2(fac * emb[(size_t)tok * 256 + t], hh, ll);
  ((ushort*)Xh)[(size_t)row * 256 + t] = hh;
  ((ushort*)Xl)[(size_t)row * 256 + t] = ll;
}

// ---------- MFMA tile primitives (split-bf16, 3-product; layouts verified r3) ----------
__device__ __forceinline__ void mma_32x32(
    const bf16* __restrict__ Ah, const bf16* __restrict__ Al,
    size_t a0, size_t a1,
    const bf16* __restrict__ Wh, const bf16* __restrict__ Wl,
    size_t b0, size_t b1, int K,
    float* __restrict__ outB, int ldo, int kg)
{
  f32x4 acc00 = {0,0,0,0}, acc01 = {0,0,0,0}, acc10 = {0,0,0,0}, acc11 = {0,0,0,0};
#pragma unroll 2
  for (int k0 = 0; k0 < K; k0 += 32) {
    const short8 a0h = *(const short8*)(Ah + a0 + k0);
    const short8 a0l = *(const short8*)(Al + a0 + k0);
    const short8 a1h = *(const short8*)(Ah + a1 + k0);
    const short8 a1l = *(const short8*)(Al + a1 + k0);
    const short8 b0h = *(const short8*)(Wh + b0 + k0);
    const short8 b0l = *(const short8*)(Wl + b0 + k0);
    const short8 b1h = *(const short8*)(Wh + b1 + k0);
    const short8 b1l = *(const short8*)(Wl + b1 + k0);
    acc00 = __builtin_amdgcn_mfma_f32_16x16x32_bf16(a0h, b0h, acc00, 0, 0, 0);
    acc01 = __builtin_amdgcn_mfma_f32_16x16x32_bf16(a0h, b1h, acc01, 0, 0, 0);
    acc10 = __builtin_amdgcn_mfma_f32_16x16x32_bf16(a1h, b0h, acc10, 0, 0, 0);
    acc11 = __builtin_amdgcn_mfma_f32_16x16x32_bf16(a1h, b1h, acc11, 0, 0, 0);
    acc00 = __builtin_amdgcn_mfma_f32_16x16x32_bf16(a0h, b0l, acc00, 0, 0, 0);
    acc01 = __builtin_amdgcn_mfma_f32_16x16x32_bf16(a0h, b1l, acc01, 0, 0, 0);
    acc10 = __builtin_amdgcn_mfma_f32_16x16x32_bf16(a1h, b0l, acc10, 0, 0, 0);
    acc11 = __builtin_amdgcn_mfma_f32_16x16x32_bf16(a1h, b1l, acc11, 0, 0, 0);
    acc00 = __builtin_amdgcn_mfma_f32_16x16x32_bf16(a0l, b0h, acc00, 0, 0, 0);
    acc01 = __builtin_amdgcn_mfma_f32_16x16x32_bf16(a0l, b1h, acc01, 0, 0, 0);
    acc10 = __builtin_amdgcn_mfma_f32_16x16x32_bf16(a1l, b0h, acc10, 0, 0, 0);
    acc11 = __builtin_amdgcn_mfma_f32_16x16x32_bf16(a1l, b1h, acc11, 0, 0, 0);
  }
#pragma unroll
  for (int r = 0; r < 4; r++) {
    outB[(size_t)(kg*4 + r) * ldo]            = acc00[r];
    outB[(size_t)(kg*4 + r) * ldo + 16]       = acc01[r];
    outB[(size_t)(16 + kg*4 + r) * ldo]       = acc10[r];
    outB[(size_t)(16 + kg*4 + r) * ldo + 16]  = acc11[r];
  }
}

__device__ __forceinline__ void mma_32x16(
    const bf16* __restrict__ Ah, const bf16* __restrict__ Al,
    size_t a0, size_t a1,
    const bf16* __restrict__ Wh, const bf16* __restrict__ Wl,
    size_t b0, int K,
    float* __restrict__ outB, int ldo, int kg)
{
  f32x4 acc0 = {0,0,0,0}, acc1 = {0,0,0,0};
#pragma unroll 2
  for (int k0 = 0; k0 < K; k0 += 32) {
    const short8 a0h = *(const short8*)(Ah + a0 + k0);
    const short8 a0l = *(const short8*)(Al + a0 + k0);
    const short8 a1h = *(const short8*)(Ah + a1 + k0);
    const short8 a1l = *(const short8*)(Al + a1 + k0);
    const short8 bh  = *(const short8*)(Wh + b0 + k0);
    const short8 bl  = *(const short8*)(Wl + b0 + k0);
    acc0 = __builtin_amdgcn_mfma_f32_16x16x32_bf16(a0h, bh, acc0, 0, 0, 0);
    acc1 = __builtin_amdgcn_mfma_f32_16x16x32_bf16(a1h, bh, acc1, 0, 0, 0);
    acc0 = __builtin_amdgcn_mfma_f32_16x16x32_bf16(a0h, bl, acc0, 0, 0, 0);
    acc1 = __builtin_amdgcn_mfma_f32_16x16x32_bf16(a1h, bl, acc1, 0, 0, 0);
    acc0 = __builtin_amdgcn_mfma_f32_16x16x32_bf16(a0l, bh, acc0, 0, 0, 0);
    acc1 = __builtin_amdgcn_mfma_f32_16x16x32_bf16(a1l, bh, acc1, 0, 0, 0);
  }
#pragma unroll
  for (int r = 0; r < 4; r++) {
    outB[(size_t)(kg*4 + r) * ldo]      = acc0[r];
    outB[(size_t)(16 + kg*4 + r) * ldo] = acc1[r];
  }
}

// phase-A tile: 128x64, wave (wr= w>>1 of 4, wc= w&1 of 2) 32x32
__device__ __forceinline__ void phaseA_tile(
    int tr, int tc, int wr, int wc, int fr, int kg,
    const bf16* Hh, const bf16* Hl, const bf16* Xh, const bf16* Xl,
    const bf16* W0h, const bf16* W0l, float* g1)
{
  const int g = tr >> 9;
  int K; const bf16 *Ah, *Al; size_t Woff;
  if (tc < 1024) {
    K = 512; Ah = Hh; Al = Hl;
    Woff = (size_t)g*917504 + (size_t)(tc>>9)*262144 + (size_t)(tc & 511)*512;
  } else {
    K = 256; Ah = Xh; Al = Xl;
    const int lc = tc - 1024;
    Woff = (size_t)g*917504 + 524288 + (size_t)(lc>>9)*131072 + (size_t)(lc & 511)*256;
  }
  const int r0 = tr + wr*32;
  const size_t a0 = (size_t)(r0 + fr)*K + kg*8, a1 = a0 + (size_t)16*K;
  const size_t b0 = (size_t)(wc*32 + fr)*K + kg*8, b1 = b0 + (size_t)16*K;
  float* outB = g1 + (size_t)r0*2560 + (tc + wc*32 + fr);
  mma_32x32(Ah, Al, a0, a1, W0h + Woff, W0l + Woff, b0, b1, K, outB, 2560, kg);
}

// ---------- argument bundle ----------
struct CoopArgs {
  const float *emb; const int *src_t, *tgt_t;
  const float *b_src, *b_tgt, *bp_src, *bp_tgt, *dist_bias, *plane_p, *plane_a;
  const int *alignment;
  float *g1, *htm, *hbuf, *mxb;
  const float4 *tokf;
  bf16 *Hh, *Hl, *Xh, *Xl, *Rh, *Rl;
  const bf16 *W0h, *W0l, *W1h, *W1l, *W2h, *W2l;
  float *outp;
};

// ---------- the persistent cooperative kernel ----------
__global__ __launch_bounds__(512, 2) void k_coop(CoopArgs A)
{
  cg::grid_group grid = cg::this_grid();
  const int bid = blockIdx.x;            // 0..255
  const int tid = threadIdx.x;           // 0..511
  const int w = tid >> 6, lane = tid & 63;
  const int fr = lane & 15, kg = lane >> 4;
  const int wrA = w >> 1, wcA = w & 1;   // phase A/E geometry (4x2 of 32x32)
  const int wrC = w >> 2, wcC = w & 3;   // phase C geometry  (2x4 of 32x16)

  // ---- phase-A tile assignment (load-balanced: 2 units/block; XCD-stable cols) ----
  int An, t0r = 0, t0c = 0, t1r = 0, t1c = 0;
  if (bid < 128) {                       // one heavy (K=512) tile
    An = 1; t0r = (bid >> 4) * 128; t0c = (bid & 15) * 64;
  } else {
    const int c8 = bid & 7, ii = (bid - 128) >> 3;
    if (ii < 8) {
      An = 2;
      const int tp0 = 2*ii, tp1 = 2*ii + 1;
      t0r = (tp0/3)*128; t0c = (16 + c8 + (tp0%3)*8) * 64;
      t1r = (tp1/3)*128; t1c = (16 + c8 + (tp1%3)*8) * 64;
    } else {
      An = 1;
      const int tp0 = 16 + (ii - 8);
      t0r = (tp0/3)*128; t0c = (16 + c8 + (tp0%3)*8) * 64;
    }
  }

  // ---- phase-B/D row (waves 0-3 each own a row) ----
  const int rowBD = bid * 4 + w;         // valid when w<4
  // persisted per-row state (B -> D, registers)
  float pz[8], puhx[8], ph[8];
  float p_xnrh = 0.f, p_axnrh = 0.f, p_y2u = 0.f, p_sh2 = 0.f;

  for (int s = 0; s < 100; s++) {
    // ======== phase A: g1 = [H|X] @ W0^T ========
    phaseA_tile(t0r, t0c, wrA, wcA, fr, kg, A.Hh, A.Hl, A.Xh, A.Xl, A.W0h, A.W0l, A.g1);
    if (An == 2)
      phaseA_tile(t1r, t1c, wrA, wcA, fr, kg, A.Hh, A.Hl, A.Xh, A.Xl, A.W0h, A.W0l, A.g1);
    grid.sync();

    // ======== phase B: gates (wave-local per row) ========
    if (w < 4) {
      const int row = rowBD, g = row >> 9, b = row & 511;
      const float* bb = g ? A.b_tgt : A.b_src;
      const float4 tf = A.tokf[(g * 512 + b) * 100 + s];
      const float xn_x = tf.y, axn_x = tf.z;
      const float* grow = A.g1 + (size_t)row * 2560;
      float h[8], whz[8], whr[8], uxz[8], uxr[8], uxh[8], bz[8], br[8];
      float r60=0, r61=0, r62=0, r63=0, r64_=0, r65=0;
#pragma unroll
      for (int q = 0; q < 2; q++) {
        const int j4 = lane + 64*q;
        const ushort4 hhv = ((const ushort4*)(A.Hh + (size_t)row*512))[j4];
        const ushort4 hlv = ((const ushort4*)(A.Hl + (size_t)row*512))[j4];
        const float4 vz = ((const float4*)grow)[j4];
        const float4 vr = ((const float4*)(grow + 512))[j4];
        const float4 uz = ((const float4*)(grow + 1024))[j4];
        const float4 ur = ((const float4*)(grow + 1536))[j4];
        const float4 uh = ((const float4*)(grow + 2048))[j4];
        const float4 vbz = ((const float4*)(bb + 1024))[j4];
        const float4 vbr = ((const float4*)bb)[j4];
#pragma unroll
        for (int i = 0; i < 4; i++) {
          const int e = q*4 + i;
          h[e]  = bu2f(U4E(hhv,i)) + bu2f(U4E(hlv,i));
          whz[e] = F4E(vz,i); whr[e] = F4E(vr,i);
          uxz[e] = F4E(uz,i); uxr[e] = F4E(ur,i); uxh[e] = F4E(uh,i);
          bz[e] = F4E(vbz,i); br[e] = F4E(vbr,i);
          r60 += h[e]*h[e];     r61 += whz[e]*whz[e]; r62 += whr[e]*whr[e];
          r63 += uxz[e]*uxz[e]; r64_ += uxr[e]*uxr[e]; r65 += uxh[e]*uxh[e];
        }
      }
      r60 = wave_sum(r60); r61 = wave_sum(r61); r62 = wave_sum(r62);
      r63 = wave_sum(r63); r64_ = wave_sum(r64_); r65 = wave_sum(r65);
      const float sh2 = r60;
      const float xn_h = sqrtf(fmaxf(sh2, EPSF)), axn_h = artanh_c(xn_h);
      const float mz = sqrtf(fmaxf(r61, EPSF)); const float tz = tanhf(mz / xn_h * axn_h);
      const float sz = (mz <= 1e-7f) ? 0.f : tz/mz; const float x2z = (mz <= 1e-7f) ? 0.f : tz*tz;
      const float mr = sqrtf(fmaxf(r62, EPSF)); const float tr_ = tanhf(mr / xn_h * axn_h);
      const float sr = (mr <= 1e-7f) ? 0.f : tr_/mr; const float x2r = (mr <= 1e-7f) ? 0.f : tr_*tr_;
      const float muz = sqrtf(fmaxf(r63, EPSF)); const float tuz = tanhf(muz / xn_x * axn_x);
      const float suz = (muz <= 1e-7f) ? 0.f : tuz/muz; const float y2z = (muz <= 1e-7f) ? 0.f : tuz*tuz;
      const float mur = sqrtf(fmaxf(r64_, EPSF)); const float tur = tanhf(mur / xn_x * axn_x);
      const float sur = (mur <= 1e-7f) ? 0.f : tur/mur; const float y2r = (mur <= 1e-7f) ? 0.f : tur*tur;
      const float muh = sqrtf(fmaxf(r65, EPSF)); const float tuh = tanhf(muh / xn_x * axn_x);
      const float suh = (muh <= 1e-7f) ? 0.f : tuh/muh; const float y2u = (muh <= 1e-7f) ? 0.f : tuh*tuh;

      float Wz[8], Uz[8], Wr[8], Ur[8];
      float dd0 = 0, dd1 = 0;
#pragma unroll
      for (int e = 0; e < 8; e++) {
        Wz[e] = sz*whz[e]; Uz[e] = suz*uxz[e];
        Wr[e] = sr*whr[e]; Ur[e] = sur*uxr[e];
        dd0 += Wz[e]*Uz[e]; dd1 += Wr[e]*Ur[e];
      }
      dd0 = wave_sum(dd0); dd1 = wave_sum(dd1);
      float t1z[8], t1r[8];
      {
        const float iv = 1.f / fmaxf(1.f + 2.f*dd0 + x2z*y2z, EPSF);
        const float c1 = 1.f + 2.f*dd0 + y2z, c2 = 1.f - x2z;
#pragma unroll
        for (int e = 0; e < 8; e++) t1z[e] = (c1*Wz[e] + c2*Uz[e]) * iv;
      }
      {
        const float iv = 1.f / fmaxf(1.f + 2.f*dd1 + x2r*y2r, EPSF);
        const float c1 = 1.f + 2.f*dd1 + y2r, c2 = 1.f - x2r;
#pragma unroll
        for (int e = 0; e < 8; e++) t1r[e] = (c1*Wr[e] + c2*Ur[e]) * iv;
      }
      float e0=0, e1=0, e2=0, e3=0, e4=0, e5=0;
#pragma unroll
      for (int e = 0; e < 8; e++) {
        e0 += t1z[e]*t1z[e]; e1 += t1z[e]*bz[e]; e2 += bz[e]*bz[e];
        e3 += t1r[e]*t1r[e]; e4 += t1r[e]*br[e]; e5 += br[e]*br[e];
      }
      e0 = wave_sum(e0); e1 = wave_sum(e1); e2 = wave_sum(e2);
      e3 = wave_sum(e3); e4 = wave_sum(e4); e5 = wave_sum(e5);
      float t2z[8], t2r[8];
      {
        const float iv = 1.f / fmaxf(1.f + 2.f*e1 + e0*e2, EPSF);
        const float c1 = 1.f + 2.f*e1 + e2, c2 = 1.f - e0;
#pragma unroll
        for (int e = 0; e < 8; e++) t2z[e] = (c1*t1z[e] + c2*bz[e]) * iv;
      }
      {
        const float iv = 1.f / fmaxf(1.f + 2.f*e4 + e3*e5, EPSF);
        const float c1 = 1.f + 2.f*e4 + e5, c2 = 1.f - e3;
#pragma unroll
        for (int e = 0; e < 8; e++) t2r[e] = (c1*t1r[e] + c2*br[e]) * iv;
      }
      float n0 = 0, n1 = 0;
#pragma unroll
      for (int e = 0; e < 8; e++) { n0 += t2z[e]*t2z[e]; n1 += t2r[e]*t2r[e]; }
      n0 = wave_sum(n0); n1 = wave_sum(n1);
      const float nz = sqrtf(fmaxf(n0, EPSF)); const float fz = artanh_c(nz) / nz;
      const float nr = sqrtf(fmaxf(n1, EPSF)); const float frg = artanh_c(nr) / nr;
      float zz[8], wx[8];
      float rw = 0;
#pragma unroll
      for (int e = 0; e < 8; e++) {
        zz[e] = sigmoidf(fz * t2z[e]);
        const float rr = sigmoidf(frg * t2r[e]);
        wx[e] = rr * h[e];
        rw += wx[e]*wx[e];
      }
      rw = wave_sum(rw);
      const float wxn = sqrtf(fmaxf(rw, EPSF));
      const float trh = tanhf(wxn / xn_h * axn_h);
      const float srh = (wxn <= 1e-7f) ? 0.f : trh / wxn;
      const float xn_rh = (wxn <= 1e-7f) ? sqrtf(EPSF) : fmaxf(trh, sqrtf(EPSF));
      const float axn_rh = artanh_c(xn_rh);
      // write R planes; persist state for phase D
#pragma unroll
      for (int q = 0; q < 2; q++) {
        ushort th[4], tl[4];
#pragma unroll
        for (int i = 0; i < 4; i++) split2(srh * wx[q*4+i], th[i], tl[i]);
        ((ushort4*)(A.Rh + (size_t)row*512))[lane + 64*q] = make_ushort4(th[0],th[1],th[2],th[3]);
        ((ushort4*)(A.Rl + (size_t)row*512))[lane + 64*q] = make_ushort4(tl[0],tl[1],tl[2],tl[3]);
      }
#pragma unroll
      for (int e = 0; e < 8; e++) { pz[e] = zz[e]; puhx[e] = suh*uxh[e]; ph[e] = h[e]; }
      p_xnrh = xn_rh; p_axnrh = axn_rh; p_y2u = y2u; p_sh2 = sh2;
    }
    grid.sync();

    // ======== phase C: htm = R @ W1^T (blocks 0-127, tile 64x64) ========
    if (bid < 128) {
      const int rows = (bid >> 3) * 64, cols = (bid & 7) * 64;
      const int g = rows >> 9;
      const size_t Woff = (size_t)g*262144 + (size_t)cols*512;
      const int r0 = rows + wrC*32;
      const size_t a0 = (size_t)(r0 + fr)*512 + kg*8, a1 = a0 + (size_t)16*512;
      const size_t b0 = (size_t)(wcC*16 + fr)*512 + kg*8;
      float* outB = A.htm + (size_t)r0*512 + (cols + wcC*16 + fr);
      mma_32x16(A.Rh, A.Rl, a0, a1, A.W1h + Woff, A.W1l + Woff, b0, 512, outB, 512, kg);
    }
    grid.sync();

    // ======== phase D: update (wave-local per row) ========
    if (w < 4) {
      const int row = rowBD, g = row >> 9, b = row & 511;
      const float* bb = g ? A.b_tgt : A.b_src;
      float mt_[8], bh[8];
      float a0s = 0, a1s = 0;
#pragma unroll
      for (int q = 0; q < 2; q++) {
        const int j4 = lane + 64*q;
        const float4 vm = ((const float4*)(A.htm + (size_t)row*512))[j4];
        const float4 vb = ((const float4*)(bb + 512))[j4];
#pragma unroll
        for (int i = 0; i < 4; i++) {
          const int e = q*4 + i;
          mt_[e] = F4E(vm,i); bh[e] = F4E(vb,i);
          a0s += mt_[e]*mt_[e]; a1s += mt_[e]*puhx[e];
        }
      }
      a0s = wave_sum(a0s); a1s = wave_sum(a1s);
      const float m = sqrtf(fmaxf(a0s, EPSF));
      const float tt = tanhf(m / p_xnrh * p_axnrh);
      const float st = (m <= 1e-7f) ? 0.f : tt/m;
      const float x2 = (m <= 1e-7f) ? 0.f : tt*tt;
      float t1[8];
      {
        const float xy = st * a1s;
        const float iv = 1.f / fmaxf(1.f + 2.f*xy + x2*p_y2u, EPSF);
        const float c1 = 1.f + 2.f*xy + p_y2u, c2 = 1.f - x2;
#pragma unroll
        for (int e = 0; e < 8; e++) t1[e] = (c1*(st*mt_[e]) + c2*puhx[e]) * iv;
      }
      float b0s = 0, b1s = 0, b2s = 0;
#pragma unroll
      for (int e = 0; e < 8; e++) { b0s += t1[e]*t1[e]; b1s += t1[e]*bh[e]; b2s += bh[e]*bh[e]; }
      b0s = wave_sum(b0s); b1s = wave_sum(b1s); b2s = wave_sum(b2s);
      float ht[8];
      {
        const float iv = 1.f / fmaxf(1.f + 2.f*b1s + b0s*b2s, EPSF);
        const float c1 = 1.f + 2.f*b1s + b2s, c2 = 1.f - b0s;
#pragma unroll
        for (int e = 0; e < 8; e++) ht[e] = (c1*t1[e] + c2*bh[e]) * iv;
      }
      float c0s = 0, c1s = 0;
#pragma unroll
      for (int e = 0; e < 8; e++) { c0s += ht[e]*ht[e]; c1s += ph[e]*ht[e]; }
      c0s = wave_sum(c0s); c1s = wave_sum(c1s);
      float delta[8];
      {
        const float xy = -c1s;
        const float iv = 1.f / fmaxf(1.f + 2.f*xy + p_sh2*c0s, EPSF);
        const float c1 = 1.f + 2.f*xy + c0s, c2 = 1.f - p_sh2;
#pragma unroll
        for (int e = 0; e < 8; e++) delta[e] = (c1*(-ph[e]) + c2*ht[e]) * iv;
      }
      float d0s = 0, d1s = 0, d2s = 0;
#pragma unroll
      for (int e = 0; e < 8; e++) {
        const float ww = pz[e]*delta[e];
        d0s += delta[e]*delta[e]; d1s += ww*ww; d2s += ph[e]*ww;
      }
      d0s = wave_sum(d0s); d1s = wave_sum(d1s); d2s = wave_sum(d2s);
      const float dn = sqrtf(fmaxf(d0s, EPSF));
      const float axnd = artanh_c(dn);
      const float wxn = sqrtf(fmaxf(d1s, EPSF));
      const float tzd = tanhf(wxn / dn * axnd);
      const float szd = (wxn <= 1e-7f) ? 0.f : tzd/wxn;
      const float y2zd = (wxn <= 1e-7f) ? 0.f : tzd*tzd;
      {
        const float xy = szd * d2s;
        const float iv = 1.f / fmaxf(1.f + 2.f*xy + p_sh2*y2zd, EPSF);
        const float c1 = 1.f + 2.f*xy + y2zd, c2 = 1.f - p_sh2;
#pragma unroll
        for (int q = 0; q < 2; q++) {
          ushort th[4], tl[4]; float hv[4];
#pragma unroll
          for (int i = 0; i < 4; i++) {
            const int e = q*4 + i;
            hv[i] = (c1*ph[e] + c2*(szd*pz[e]*delta[e])) * iv;
            split2(hv[i], th[i], tl[i]);
          }
          ((ushort4*)(A.Hh + (size_t)row*512))[lane + 64*q] = make_ushort4(th[0],th[1],th[2],th[3]);
          ((ushort4*)(A.Hl + (size_t)row*512))[lane + 64*q] = make_ushort4(tl[0],tl[1],tl[2],tl[3]);
          if (s == 99)
            ((float4*)(A.hbuf + (size_t)row*512))[lane + 64*q] = make_float4(hv[0],hv[1],hv[2],hv[3]);
        }
      }
      if (s + 1 < 100) {
        const int tok = (g ? A.tgt_t : A.src_t)[b*100 + s + 1];
        const float fac = A.tokf[(g*512 + b)*100 + s + 1].x;
        const float4 ev = ((const float4*)(A.emb + (size_t)tok*256))[lane];
        ushort th[4], tl[4];
#pragma unroll
        for (int i = 0; i < 4; i++) split2(fac * F4E(ev,i), th[i], tl[i]);
        ((ushort4*)(A.Xh + (size_t)row*256))[lane] = make_ushort4(th[0],th[1],th[2],th[3]);
        ((ushort4*)(A.Xl + (size_t)row*256))[lane] = make_ushort4(tl[0],tl[1],tl[2],tl[3]);
      }
    }
    grid.sync();
  }

  // ======== phase E: mxb = proj (blocks 0-31, tile 128x64) ========
  if (bid < 32) {
    const int erow = (bid >> 3) * 128, ecol = (bid & 7) * 64;
    const int mat = (bid & 7) >> 2;                 // 0=src cols, 1=tgt cols
    const int colM = ((bid & 7) & 3) * 64;
    const size_t Woff = (size_t)mat*131072 + (size_t)colM*512;
    const int r_l0 = erow + wrA*32 + fr, r_l1 = r_l0 + 16;
    const int arow0 = mat ? (512 + A.alignment[r_l0]) : r_l0;
    const int arow1 = mat ? (512 + A.alignment[r_l1]) : r_l1;
    const size_t a0 = (size_t)arow0*512 + kg*8, a1 = (size_t)arow1*512 + kg*8;
    const size_t b0 = (size_t)(wcA*32 + fr)*512 + kg*8, b1 = b0 + (size_t)16*512;
    float* outB = A.mxb + (size_t)(erow + wrA*32)*512 + (ecol + wcA*32 + fr);
    mma_32x32(A.Hh, A.Hl, a0, a1, A.W2h + Woff, A.W2l + Woff, b0, b1, 512, outB, 512, kg);
  }
  grid.sync();

  // ======== phase F: head (waves 0-1, batch fb = bid*2+w) ========
  if (w < 2) {
    const int fb = bid*2 + w;
    const int ar = 512 + A.alignment[fb];
    float hs[8], htg[8];
    float a0 = 0, a1 = 0, a2 = 0;
#pragma unroll
    for (int q = 0; q < 2; q++) {
      const int j4 = lane + 64*q;
      const float4 v1 = ((const float4*)(A.hbuf + (size_t)fb*512))[j4];
      const float4 v2 = ((const float4*)(A.hbuf + (size_t)ar*512))[j4];
#pragma unroll
      for (int i = 0; i < 4; i++) {
        const int e = q*4 + i;
        hs[e] = F4E(v1,i); htg[e] = F4E(v2,i);
        a0 += hs[e]*hs[e]; a1 += htg[e]*htg[e]; a2 += hs[e]*htg[e];
      }
    }
    float mxs[4], mxt[4], bps[4], bpt[4], db[4], pp0[4], pp1[4], pa0[4], pa1[4];
    {
      const float4 vm0 = ((const float4*)(A.mxb + (size_t)fb*512))[lane];
      const float4 vm1 = ((const float4*)(A.mxb + (size_t)fb*512 + 256))[lane];
      const float4 vbs = ((const float4*)A.bp_src)[lane];
      const float4 vbt = ((const float4*)A.bp_tgt)[lane];
      const float4 vdb = ((const float4*)A.dist_bias)[lane];
      const float4 vp0 = ((const float4*)A.plane_p)[lane];
      const float4 vp1 = ((const float4*)(A.plane_p + 256))[lane];
      const float4 va0 = ((const float4*)A.plane_a)[lane];
      const float4 va1 = ((const float4*)(A.plane_a + 256))[lane];
#pragma unroll
      for (int i = 0; i < 4; i++) {
        mxs[i] = F4E(vm0,i); mxt[i] = F4E(vm1,i);
        bps[i] = F4E(vbs,i); bpt[i] = F4E(vbt,i); db[i] = F4E(vdb,i);
        pp0[i] = F4E(vp0,i); pp1[i] = F4E(vp1,i);
        pa0[i] = F4E(va0,i); pa1[i] = F4E(va1,i);
      }
    }
    float a3 = 0, a4 = 0;
#pragma unroll
    for (int i = 0; i < 4; i++) { a3 += mxs[i]*mxs[i]; a4 += mxt[i]*mxt[i]; }
    a0 = wave_sum(a0); a1 = wave_sum(a1); a2 = wave_sum(a2);
    a3 = wave_sum(a3); a4 = wave_sum(a4);
    const float shs = a0, sht = a1, dot_st = a2;
    const float xns = sqrtf(fmaxf(shs, EPSF)), axns = artanh_c(xns);
    const float xnt = sqrtf(fmaxf(sht, EPSF)), axnt = artanh_c(xnt);
    const float ms = sqrtf(fmaxf(a3, EPSF)); const float ts = tanhf(ms / xns * axns);
    const float ss = (ms <= 1e-7f) ? 0.f : ts/ms; const float x2s = (ms <= 1e-7f) ? 0.f : ts*ts;
    const float mt = sqrtf(fmaxf(a4, EPSF)); const float tt = tanhf(mt / xnt * axnt);
    const float st = (mt <= 1e-7f) ? 0.f : tt/mt; const float x2t = (mt <= 1e-7f) ? 0.f : tt*tt;
    float vs[4], vt[4];
#pragma unroll
    for (int i = 0; i < 4; i++) { vs[i] = ss*mxs[i]; vt[i] = st*mxt[i]; }
    float rb0=0, rb1=0, rb2=0, rb3=0, rb4=0;
#pragma unroll
    for (int i = 0; i < 4; i++) {
      rb0 += bps[i]*bps[i]; rb1 += vs[i]*bps[i];
      rb2 += bpt[i]*bpt[i]; rb3 += vt[i]*bpt[i]; rb4 += db[i]*db[i];
    }
    rb0 = wave_sum(rb0); rb1 = wave_sum(rb1); rb2 = wave_sum(rb2);
    rb3 = wave_sum(rb3); rb4 = wave_sum(rb4);
    float ps[4], pt[4];
    {
      const float iv = 1.f / fmaxf(1.f + 2.f*rb1 + x2s*rb0, EPSF);
      const float c1 = 1.f + 2.f*rb1 + rb0, c2 = 1.f - x2s;
#pragma unroll
      for (int i = 0; i < 4; i++) ps[i] = (c1*vs[i] + c2*bps[i]) * iv;
    }
    {
      const float iv = 1.f / fmaxf(1.f + 2.f*rb3 + x2t*rb2, EPSF);
      const float c1 = 1.f + 2.f*rb3 + rb2, c2 = 1.f - x2t;
#pragma unroll
      for (int i = 0; i < 4; i++) pt[i] = (c1*vt[i] + c2*bpt[i]) * iv;
    }
    float rc0 = 0, rc1 = 0;
#pragma unroll
    for (int i = 0; i < 4; i++) { rc0 += ps[i]*ps[i]; rc1 += pt[i]*pt[i]; }
    rc0 = wave_sum(rc0); rc1 = wave_sum(rc1);
    {
      const float n = sqrtf(fmaxf(rc0, EPSF));
      if (n > 0.999f) { const float sc = 0.999f/n;
#pragma unroll
        for (int i = 0; i < 4; i++) ps[i] *= sc; }
    }
    {
      const float n = sqrtf(fmaxf(rc1, EPSF));
      if (n > 0.999f) { const float sc = 0.999f/n;
#pragma unroll
        for (int i = 0; i < 4; i++) pt[i] *= sc; }
    }
    float df2 = 0;
    {
      const float xy = -dot_st;
      const float iv = 1.f / fmaxf(1.f + 2.f*xy + shs*sht, EPSF);
      const float c1 = 1.f + 2.f*xy + sht, c2 = 1.f - shs;
#pragma unroll
      for (int e = 0; e < 8; e++) { const float d = (c1*(-hs[e]) + c2*htg[e]) * iv; df2 += d*d; }
    }
    float rd0=0, rd1=0, rd2=0;
#pragma unroll
    for (int i = 0; i < 4; i++) { rd0 += ps[i]*ps[i]; rd1 += pt[i]*pt[i]; rd2 += ps[i]*pt[i]; }
    rd0 = wave_sum(rd0); rd1 = wave_sum(rd1); rd2 = wave_sum(rd2);
    const float rd3 = wave_sum(df2);
    float pr[4];
    {
      const float iv = 1.f / fmaxf(1.f + 2.f*rd2 + rd0*rd1, EPSF);
      const float c1 = 1.f + 2.f*rd2 + rd1, c2 = 1.f - rd0;
#pragma unroll
      for (int i = 0; i < 4; i++) pr[i] = (c1*ps[i] + c2*pt[i]) * iv;
    }
    const float dn = sqrtf(fmaxf(rd3, EPSF));
    const float dist = 2.f * artanh_c(dn);
    const float d2v = dist * dist;
    const float dbn = sqrtf(fmaxf(rb4, EPSF));
    const float bscale = tanhf(d2v * artanh_c(dbn)) / dbn;
    float biasv[4];
#pragma unroll
    for (int i = 0; i < 4; i++) biasv[i] = bscale * db[i];
    float re0=0, re1=0, re2=0;
#pragma unroll
    for (int i = 0; i < 4; i++) { re0 += pr[i]*pr[i]; re1 += biasv[i]*biasv[i]; re2 += pr[i]*biasv[i]; }
    re0 = wave_sum(re0); re1 = wave_sum(re1); re2 = wave_sum(re2);
    float pr2[4];
    {
      const float iv = 1.f / fmaxf(1.f + 2.f*re2 + re0*re1, EPSF);
      const float c1 = 1.f + 2.f*re2 + re1, c2 = 1.f - re0;
#pragma unroll
      for (int i = 0; i < 4; i++) pr2[i] = (c1*pr[i] + c2*biasv[i]) * iv;
    }
    float rf0=0, rf1=0, rf2=0, rf3=0, rf4=0;
#pragma unroll
    for (int i = 0; i < 4; i++) {
      rf0 += pp0[i]*pp0[i]; rf1 += pp0[i]*pr2[i];
      rf2 += pp1[i]*pp1[i]; rf3 += pp1[i]*pr2[i]; rf4 += pr2[i]*pr2[i];
    }
    rf0 = wave_sum(rf0); rf1 = wave_sum(rf1); rf2 = wave_sum(rf2);
    rf3 = wave_sum(rf3); rf4 = wave_sum(rf4);
    float d0v[4], d1v[4];
    {
      const float xy = -rf1;
      const float iv = 1.f / fmaxf(1.f + 2.f*xy + rf0*rf4, EPSF);
      const float c1 = 1.f + 2.f*xy + rf4, c2 = 1.f - rf0;
#pragma unroll
      for (int i = 0; i < 4; i++) d0v[i] = (c1*(-pp0[i]) + c2*pr2[i]) * iv;
    }
    {
      const float xy = -rf3;
      const float iv = 1.f / fmaxf(1.f + 2.f*xy + rf2*rf4, EPSF);
      const float c1 = 1.f + 2.f*xy + rf4, c2 = 1.f - rf2;
#pragma unroll
      for (int i = 0; i < 4; i++) d1v[i] = (c1*(-pp1[i]) + c2*pr2[i]) * iv;
    }
    float rg0=0, rg1=0, rg2=0, rg3=0, rg4=0, rg5=0;
#pragma unroll
    for (int i = 0; i < 4; i++) {
      rg0 += d0v[i]*d0v[i]; rg1 += d0v[i]*pa0[i]; rg2 += pa0[i]*pa0[i];
      rg3 += d1v[i]*d1v[i]; rg4 += d1v[i]*pa1[i]; rg5 += pa1[i]*pa1[i];
    }
    rg0 = wave_sum(rg0); rg1 = wave_sum(rg1); rg2 = wave_sum(rg2);
    rg3 = wave_sum(rg3); rg4 = wave_sum(rg4); rg5 = wave_sum(rg5);
    if (lane == 0) {
      const float an0 = sqrtf(fmaxf(rg2, EPSF));
      const float an1 = sqrtf(fmaxf(rg5, EPSF));
      A.outp[fb*2 + 0] = asinhf(2.f * rg1 / fmaxf((1.f - rg0) * an0, EPSF));
      A.outp[fb*2 + 1] = asinhf(2.f * rg4 / fmaxf((1.f - rg3) * an1, EPSF));
    }
  }
}

// ---------- launch ----------
extern "C" void kernel_launch(void* const* d_in, const int* in_sizes, int n_in,
                              void* d_out, int out_size, void* d_ws, size_t ws_size,
                              hipStream_t stream) {
  const float* emb       = (const float*)d_in[0];
  const float* w_ih_src  = (const float*)d_in[1];
  const float* w_hh_src  = (const float*)d_in[2];
  const float* b_src     = (const float*)d_in[3];
  const float* w_ih_tgt  = (const float*)d_in[4];
  const float* w_hh_tgt  = (const float*)d_in[5];
  const float* b_tgt     = (const float*)d_in[6];
  const float* wp_src    = (const float*)d_in[7];
  const float* bp_src    = (const float*)d_in[8];
  const float* wp_tgt    = (const float*)d_in[9];
  const float* bp_tgt    = (const float*)d_in[10];
  const float* dist_bias = (const float*)d_in[11];
  const float* plane_p   = (const float*)d_in[12];
  const float* plane_a   = (const float*)d_in[13];
  const int* src_t       = (const int*)d_in[14];
  const int* tgt_t       = (const int*)d_in[15];
  const int* alignment   = (const int*)d_in[16];
  float* outp            = (float*)d_out;

  char* wsb = (char*)d_ws;
  float*  g1   = (float*)(wsb + 0);              // [1024][2560] f32
  float*  htm  = (float*)(wsb + 10485760);       // [1024][512]  f32
  float*  hbuf = (float*)(wsb + 12582912);       // [1024][512]  f32
  float*  mxb  = (float*)(wsb + 14680064);       // [512][512]   f32
  float4* tokf = (float4*)(wsb + 15728640);      // 102400 float4
  bf16*   Hh   = (bf16*)(wsb + 17367040);        // [1024][512]
  bf16*   Hl   = (bf16*)(wsb + 18415616);
  bf16*   Xh   = (bf16*)(wsb + 19464192);        // [1024][256]
  bf16*   Xl   = (bf16*)(wsb + 19988480);
  bf16*   Rh   = (bf16*)(wsb + 20512768);        // [1024][512]
  bf16*   Rl   = (bf16*)(wsb + 21561344);
  bf16*   W0h  = (bf16*)(wsb + 22609920);        // 1835008
  bf16*   W0l  = (bf16*)(wsb + 26279936);
  bf16*   W1h  = (bf16*)(wsb + 29949952);        // 524288
  bf16*   W1l  = (bf16*)(wsb + 30998528);
  bf16*   W2h  = (bf16*)(wsb + 32047104);        // 262144
  bf16*   W2l  = (bf16*)(wsb + 32571392);        // end 33095680

  hipMemsetAsync(Hh, 0, 1048576, stream);
  hipMemsetAsync(Hl, 0, 1048576, stream);
  k_wconv<<<10240, 256, 0, stream>>>(w_ih_src, w_hh_src, w_ih_tgt, w_hh_tgt,
                                     wp_src, wp_tgt, W0h, W0l, W1h, W1l, W2h, W2l);
  k_tok<<<25600, 256, 0, stream>>>(emb, src_t, tgt_t, tokf);
  kx0<<<1024, 256, 0, stream>>>(emb, src_t, tgt_t, tokf, Xh, Xl);

  CoopArgs A;
  A.emb = emb; A.src_t = src_t; A.tgt_t = tgt_t;
  A.b_src = b_src; A.b_tgt = b_tgt; A.bp_src = bp_src; A.bp_tgt = bp_tgt;
  A.dist_bias = dist_bias; A.plane_p = plane_p; A.plane_a = plane_a;
  A.alignment = alignment;
  A.g1 = g1; A.htm = htm; A.hbuf = hbuf; A.mxb = mxb; A.tokf = tokf;
  A.Hh = Hh; A.Hl = Hl; A.Xh = Xh; A.Xl = Xl; A.Rh = Rh; A.Rl = Rl;
  A.W0h = W0h; A.W0l = W0l; A.W1h = W1h; A.W1l = W1l; A.W2h = W2h; A.W2l = W2l;
  A.outp = outp;
  void* kargs[] = { &A };
  hipLaunchCooperativeKernel((void*)k_coop, dim3(256), dim3(512), kargs, 0, stream);
}

// Round 5
// 15690.138 us; speedup vs baseline: 1.1875x; 1.1875x over previous
//
#include <hip/hip_runtime.h>
#include <hip/hip_bf16.h>

#define EPSF 1e-15f

typedef __hip_bfloat16 bf16;
typedef __attribute__((ext_vector_type(8))) short short8;
typedef __attribute__((ext_vector_type(4))) float f32x4;

#define F4E(v,i) ((i)==0?(v).x:((i)==1?(v).y:((i)==2?(v).z:(v).w)))
#define U4E(v,i) ((i)==0?(v).x:((i)==1?(v).y:((i)==2?(v).z:(v).w)))

// ---------- helpers ----------
__device__ __forceinline__ float artanh_c(float x) {
  x = fminf(fmaxf(x, -1.f + 1e-5f), 1.f - 1e-5f);
  return 0.5f * log1pf(2.f * x / (1.f - x));
}
__device__ __forceinline__ float sigmoidf(float x) { return 1.f / (1.f + expf(-x)); }
__device__ __forceinline__ float wave_sum(float x) {
#pragma unroll
  for (int o = 32; o > 0; o >>= 1) x += __shfl_xor(x, o);
  return x;
}
__device__ __forceinline__ float bu2f(ushort u) { return __uint_as_float(((unsigned)u) << 16); }
__device__ __forceinline__ ushort f2bu(float v) {
  bf16 t = __float2bfloat16(v);
  union { bf16 b; ushort u; } c; c.b = t; return c.u;
}
__device__ __forceinline__ void split2(float v, ushort& h, ushort& l) {
  h = f2bu(v); l = f2bu(v - bu2f(h));
}

// ---------- weight packing: fragment-major split-bf16 (once per call) ----------
// W0 per GRU (917504): h-part (cols 0-1023 = Whz|Whr, K=512) then x-part
// (cols 0-1535 = Uxz|Uxr|Uxh, K=256). Packed unit = (col-tile, ki): 64 lanes x 8 shorts,
// lane l covers col=ct*16+(l&15), k=ki*32+(l>>4)*8.. so a wave's B-frag load is 1KB coalesced.
__global__ __launch_bounds__(256) void k_wconv(
    const float* __restrict__ w_ih_src, const float* __restrict__ w_hh_src,
    const float* __restrict__ w_ih_tgt, const float* __restrict__ w_hh_tgt,
    bf16* __restrict__ W0h, bf16* __restrict__ W0l,
    bf16* __restrict__ W1h, bf16* __restrict__ W1l)
{
  const int idx = blockIdx.x * 256 + threadIdx.x;   // 2359296 total
  float v;
  if (idx < 1835008) {
    const int g = idx / 917504, p = idx % 917504;
    const float* wih = g ? w_ih_tgt : w_ih_src;
    const float* whh = g ? w_hh_tgt : w_hh_src;
    if (p < 524288) {                 // h-part, K=512
      const int unit = p >> 9, r = p & 511, lane = r >> 3, e = r & 7;
      const int ct = unit >> 4, ki = unit & 15;
      const int col = ct*16 + (lane & 15), k = ki*32 + (lane >> 4)*8 + e;
      v = (col < 512) ? whh[524288 + col*512 + k]      // Whz = w_hh[2]
                      : whh[(col - 512)*512 + k];      // Whr = w_hh[0]
    } else {                          // x-part, K=256
      const int q = p - 524288;
      const int unit = q >> 9, r = q & 511, lane = r >> 3, e = r & 7;
      const int ct = unit >> 3, ki = unit & 7;
      const int col = ct*16 + (lane & 15), k = ki*32 + (lane >> 4)*8 + e;
      v = (col < 512)  ? wih[262144 + col*256 + k]           // Uxz = w_ih[2]
        : (col < 1024) ? wih[(col - 512)*256 + k]            // Uxr = w_ih[0]
                       : wih[131072 + (col - 1024)*256 + k]; // Uxh = w_ih[1]
    }
    ushort hh, ll; split2(v, hh, ll);
    ((ushort*)W0h)[idx] = hh; ((ushort*)W0l)[idx] = ll;
  } else {
    const int j = idx - 1835008;
    if (j >= 524288) return;
    const int g = j >> 18, p = j & 262143;
    const float* whh = g ? w_hh_tgt : w_hh_src;
    const int unit = p >> 9, r = p & 511, lane = r >> 3, e = r & 7;
    const int ct = unit >> 4, ki = unit & 15;
    const int col = ct*16 + (lane & 15), k = ki*32 + (lane >> 4)*8 + e;
    v = whh[262144 + col*512 + k];                     // W_hh_ = w_hh[1]
    ushort hh, ll; split2(v, hh, ll);
    ((ushort*)W1h)[j] = hh; ((ushort*)W1l)[j] = ll;
  }
}

// ---------- row-local gate math (pure registers; verified round 2-4) ----------
__device__ __forceinline__ void gate_row(
    const float h[8], const float whz[8], const float whr[8],
    const float uxz[8], const float uxr[8], const float uxh[8],
    const float bz[8], const float br[8],
    float xn_x, float axn_x,
    float rh[8], float pz[8], float puhx[8],
    float& o_xnrh, float& o_axnrh, float& o_y2u, float& o_sh2)
{
  float r60=0, r61=0, r62=0, r63=0, r64_=0, r65=0;
#pragma unroll
  for (int e = 0; e < 8; e++) {
    r60 += h[e]*h[e];     r61 += whz[e]*whz[e]; r62 += whr[e]*whr[e];
    r63 += uxz[e]*uxz[e]; r64_ += uxr[e]*uxr[e]; r65 += uxh[e]*uxh[e];
  }
  r60 = wave_sum(r60); r61 = wave_sum(r61); r62 = wave_sum(r62);
  r63 = wave_sum(r63); r64_ = wave_sum(r64_); r65 = wave_sum(r65);
  const float sh2 = r60;
  const float xn_h = sqrtf(fmaxf(sh2, EPSF)), axn_h = artanh_c(xn_h);
  const float mz = sqrtf(fmaxf(r61, EPSF)); const float tz = tanhf(mz / xn_h * axn_h);
  const float sz = (mz <= 1e-7f) ? 0.f : tz/mz; const float x2z = (mz <= 1e-7f) ? 0.f : tz*tz;
  const float mr = sqrtf(fmaxf(r62, EPSF)); const float tr_ = tanhf(mr / xn_h * axn_h);
  const float sr = (mr <= 1e-7f) ? 0.f : tr_/mr; const float x2r = (mr <= 1e-7f) ? 0.f : tr_*tr_;
  const float muz = sqrtf(fmaxf(r63, EPSF)); const float tuz = tanhf(muz / xn_x * axn_x);
  const float suz = (muz <= 1e-7f) ? 0.f : tuz/muz; const float y2z = (muz <= 1e-7f) ? 0.f : tuz*tuz;
  const float mur = sqrtf(fmaxf(r64_, EPSF)); const float tur = tanhf(mur / xn_x * axn_x);
  const float sur = (mur <= 1e-7f) ? 0.f : tur/mur; const float y2r = (mur <= 1e-7f) ? 0.f : tur*tur;
  const float muh = sqrtf(fmaxf(r65, EPSF)); const float tuh = tanhf(muh / xn_x * axn_x);
  const float suh = (muh <= 1e-7f) ? 0.f : tuh/muh; const float y2u = (muh <= 1e-7f) ? 0.f : tuh*tuh;

  float dd0 = 0, dd1 = 0;
#pragma unroll
  for (int e = 0; e < 8; e++) {
    dd0 += (sz*whz[e])*(suz*uxz[e]);
    dd1 += (sr*whr[e])*(sur*uxr[e]);
  }
  dd0 = wave_sum(dd0); dd1 = wave_sum(dd1);
  float t1z[8], t1r[8];
  {
    const float iv = 1.f / fmaxf(1.f + 2.f*dd0 + x2z*y2z, EPSF);
    const float c1 = 1.f + 2.f*dd0 + y2z, c2 = 1.f - x2z;
#pragma unroll
    for (int e = 0; e < 8; e++) t1z[e] = (c1*(sz*whz[e]) + c2*(suz*uxz[e])) * iv;
  }
  {
    const float iv = 1.f / fmaxf(1.f + 2.f*dd1 + x2r*y2r, EPSF);
    const float c1 = 1.f + 2.f*dd1 + y2r, c2 = 1.f - x2r;
#pragma unroll
    for (int e = 0; e < 8; e++) t1r[e] = (c1*(sr*whr[e]) + c2*(sur*uxr[e])) * iv;
  }
  float e0=0, e1=0, e2=0, e3=0, e4=0, e5=0;
#pragma unroll
  for (int e = 0; e < 8; e++) {
    e0 += t1z[e]*t1z[e]; e1 += t1z[e]*bz[e]; e2 += bz[e]*bz[e];
    e3 += t1r[e]*t1r[e]; e4 += t1r[e]*br[e]; e5 += br[e]*br[e];
  }
  e0 = wave_sum(e0); e1 = wave_sum(e1); e2 = wave_sum(e2);
  e3 = wave_sum(e3); e4 = wave_sum(e4); e5 = wave_sum(e5);
  float t2z[8], t2r[8];
  {
    const float iv = 1.f / fmaxf(1.f + 2.f*e1 + e0*e2, EPSF);
    const float c1 = 1.f + 2.f*e1 + e2, c2 = 1.f - e0;
#pragma unroll
    for (int e = 0; e < 8; e++) t2z[e] = (c1*t1z[e] + c2*bz[e]) * iv;
  }
  {
    const float iv = 1.f / fmaxf(1.f + 2.f*e4 + e3*e5, EPSF);
    const float c1 = 1.f + 2.f*e4 + e5, c2 = 1.f - e3;
#pragma unroll
    for (int e = 0; e < 8; e++) t2r[e] = (c1*t1r[e] + c2*br[e]) * iv;
  }
  float n0 = 0, n1 = 0;
#pragma unroll
  for (int e = 0; e < 8; e++) { n0 += t2z[e]*t2z[e]; n1 += t2r[e]*t2r[e]; }
  n0 = wave_sum(n0); n1 = wave_sum(n1);
  const float nz = sqrtf(fmaxf(n0, EPSF)); const float fz = artanh_c(nz) / nz;
  const float nr = sqrtf(fmaxf(n1, EPSF)); const float frg = artanh_c(nr) / nr;
  float wx[8];
  float rw = 0;
#pragma unroll
  for (int e = 0; e < 8; e++) {
    pz[e] = sigmoidf(fz * t2z[e]);
    const float rr = sigmoidf(frg * t2r[e]);
    wx[e] = rr * h[e];
    rw += wx[e]*wx[e];
  }
  rw = wave_sum(rw);
  const float wxn = sqrtf(fmaxf(rw, EPSF));
  const float trh = tanhf(wxn / xn_h * axn_h);
  const float srh = (wxn <= 1e-7f) ? 0.f : trh / wxn;
  const float xn_rh = (wxn <= 1e-7f) ? sqrtf(EPSF) : fmaxf(trh, sqrtf(EPSF));
#pragma unroll
  for (int e = 0; e < 8; e++) { rh[e] = srh * wx[e]; puhx[e] = suh * uxh[e]; }
  o_xnrh = xn_rh; o_axnrh = artanh_c(xn_rh); o_y2u = y2u; o_sh2 = sh2;
}

// ---------- row-local update math ----------
__device__ __forceinline__ void update_row(
    const float mt_[8], const float bh[8],
    const float pz[8], const float puhx[8], const float phv[8],
    float p_xnrh, float p_axnrh, float p_y2u, float p_sh2,
    float hnew[8])
{
  float a0s = 0, a1s = 0;
#pragma unroll
  for (int e = 0; e < 8; e++) { a0s += mt_[e]*mt_[e]; a1s += mt_[e]*puhx[e]; }
  a0s = wave_sum(a0s); a1s = wave_sum(a1s);
  const float m = sqrtf(fmaxf(a0s, EPSF));
  const float tt = tanhf(m / p_xnrh * p_axnrh);
  const float st = (m <= 1e-7f) ? 0.f : tt/m;
  const float x2 = (m <= 1e-7f) ? 0.f : tt*tt;
  float t1[8];
  {
    const float xy = st * a1s;
    const float iv = 1.f / fmaxf(1.f + 2.f*xy + x2*p_y2u, EPSF);
    const float c1 = 1.f + 2.f*xy + p_y2u, c2 = 1.f - x2;
#pragma unroll
    for (int e = 0; e < 8; e++) t1[e] = (c1*(st*mt_[e]) + c2*puhx[e]) * iv;
  }
  float b0s = 0, b1s = 0, b2s = 0;
#pragma unroll
  for (int e = 0; e < 8; e++) { b0s += t1[e]*t1[e]; b1s += t1[e]*bh[e]; b2s += bh[e]*bh[e]; }
  b0s = wave_sum(b0s); b1s = wave_sum(b1s); b2s = wave_sum(b2s);
  float ht[8];
  {
    const float iv = 1.f / fmaxf(1.f + 2.f*b1s + b0s*b2s, EPSF);
    const float c1 = 1.f + 2.f*b1s + b2s, c2 = 1.f - b0s;
#pragma unroll
    for (int e = 0; e < 8; e++) ht[e] = (c1*t1[e] + c2*bh[e]) * iv;
  }
  float c0s = 0, c1s = 0;
#pragma unroll
  for (int e = 0; e < 8; e++) { c0s += ht[e]*ht[e]; c1s += phv[e]*ht[e]; }
  c0s = wave_sum(c0s); c1s = wave_sum(c1s);
  float delta[8];
  {
    const float xy = -c1s;
    const float iv = 1.f / fmaxf(1.f + 2.f*xy + p_sh2*c0s, EPSF);
    const float c1 = 1.f + 2.f*xy + c0s, c2 = 1.f - p_sh2;
#pragma unroll
    for (int e = 0; e < 8; e++) delta[e] = (c1*(-phv[e]) + c2*ht[e]) * iv;
  }
  float d0s = 0, d1s = 0, d2s = 0;
#pragma unroll
  for (int e = 0; e < 8; e++) {
    const float ww = pz[e]*delta[e];
    d0s += delta[e]*delta[e]; d1s += ww*ww; d2s += phv[e]*ww;
  }
  d0s = wave_sum(d0s); d1s = wave_sum(d1s); d2s = wave_sum(d2s);
  const float dn = sqrtf(fmaxf(d0s, EPSF));
  const float axnd = artanh_c(dn);
  const float wxn = sqrtf(fmaxf(d1s, EPSF));
  const float tzd = tanhf(wxn / dn * axnd);
  const float szd = (wxn <= 1e-7f) ? 0.f : tzd/wxn;
  const float y2zd = (wxn <= 1e-7f) ? 0.f : tzd*tzd;
  const float xy = szd * d2s;
  const float iv = 1.f / fmaxf(1.f + 2.f*xy + p_sh2*y2zd, EPSF);
  const float c1 = 1.f + 2.f*xy + y2zd, c2 = 1.f - p_sh2;
#pragma unroll
  for (int e = 0; e < 8; e++) hnew[e] = (c1*phv[e] + c2*(szd*pz[e]*delta[e])) * iv;
}

// ---------- the row-local persistent RNN kernel: 64 blocks x 16 rows, no grid sync ----------
// LDS map (64KB): [0,16K)=H_hi [16K,32K)=H_lo; M=[32K,64K): ph1 x_hi@32K(8K) x_lo@40K(8K);
// ph2-3 rh_hi@32K(16K) rh_lo@48K(16K). XOR swizzle byte^=((row&7)<<4) on all act planes.
__global__ __launch_bounds__(512) void k_rnn(
    const float* __restrict__ emb, const int* __restrict__ src_t,
    const int* __restrict__ tgt_t, const float* __restrict__ b_src,
    const float* __restrict__ b_tgt,
    const bf16* __restrict__ W0h_, const bf16* __restrict__ W0l_,
    const bf16* __restrict__ W1h_, const bf16* __restrict__ W1l_,
    float* __restrict__ yws, float* __restrict__ htmws,
    float* __restrict__ hbuf)
{
  const int bid = blockIdx.x, tid = threadIdx.x;
  const int w = tid >> 6, lane = tid & 63;
  const int fr = lane & 15, kg = lane >> 4;
  const int g = bid & 1, b16 = bid >> 1;     // GRU by parity -> XCD weight locality
  const bf16* W0h = W0h_ + (size_t)g * 917504;
  const bf16* W0l = W0l_ + (size_t)g * 917504;
  const bf16* W1h = W1h_ + (size_t)g * 262144;
  const bf16* W1l = W1l_ + (size_t)g * 262144;
  const int* toks = g ? tgt_t : src_t;
  const float* bb = g ? b_tgt : b_src;
  float* ysl = yws + (size_t)bid * 40960;    // [16][2560] f32, block-private
  float* hsl = htmws + (size_t)bid * 8192;   // [16][512]  f32, block-private

  __shared__ char L[65536];
  for (int i = tid; i < 2048; i += 512) ((float4*)L)[i] = make_float4(0.f,0.f,0.f,0.f);

  float p_xnx[2], p_axnx[2];
  float pz_[2][8], puhx_[2][8], phh_[2][8];
  float p_xnrh[2], p_axnrh[2], p_y2u[2], p_sh2[2];

  // initial x (s=0) + norms
#define XLOAD(RI, TOKIDX)                                                        \
  {                                                                              \
    const int row = w*2 + (RI);                                                  \
    const int tok = toks[(b16*16 + row)*100 + (TOKIDX)];                         \
    const float4 ev = ((const float4*)(emb + (size_t)tok * 256))[lane];          \
    float ss = ev.x*ev.x + ev.y*ev.y + ev.z*ev.z + ev.w*ev.w;                    \
    ss = wave_sum(ss);                                                           \
    const float un = sqrtf(fmaxf(ss, EPSF));                                     \
    const float fac = tanhf(un) / un;                                            \
    const float xnv = sqrtf(fmaxf(fac*fac*ss, EPSF));                            \
    p_xnx[RI] = xnv; p_axnx[RI] = artanh_c(xnv);                                 \
    ushort th[4], tl[4];                                                         \
    split2(fac*ev.x, th[0], tl[0]); split2(fac*ev.y, th[1], tl[1]);              \
    split2(fac*ev.z, th[2], tl[2]); split2(fac*ev.w, th[3], tl[3]);              \
    const unsigned xo = (unsigned)((row*512 + lane*8) ^ ((row & 7) << 4));       \
    *(ushort4*)(L + 32768 + xo) = make_ushort4(th[0],th[1],th[2],th[3]);         \
    *(ushort4*)(L + 40960 + xo) = make_ushort4(tl[0],tl[1],tl[2],tl[3]);         \
  }

  XLOAD(0, 0)
  XLOAD(1, 0)
  __syncthreads();

  for (int s = 0; s < 100; s++) {
    // ===== phase 1a: y[:, 0:1024] = H @ {Whz|Whr}^T  (K=512, 8 tiles/wave) =====
    {
      const f32x4 z4 = {0.f,0.f,0.f,0.f};
      f32x4 acc[8];
#pragma unroll
      for (int t = 0; t < 8; t++) acc[t] = z4;
      for (int ki = 0; ki < 16; ki++) {
        const unsigned ao = (unsigned)((fr*1024 + ki*64 + kg*16) ^ ((fr & 7) << 4));
        const short8 aHi = *(const short8*)(L + ao);
        const short8 aLo = *(const short8*)(L + 16384 + ao);
#pragma unroll
        for (int t = 0; t < 8; t++) {
          const size_t u = (size_t)(((w*8 + t)*16 + ki)*512) + lane*8;
          const short8 bHi = *(const short8*)(W0h + u);
          const short8 bLo = *(const short8*)(W0l + u);
          acc[t] = __builtin_amdgcn_mfma_f32_16x16x32_bf16(aHi, bHi, acc[t], 0,0,0);
          acc[t] = __builtin_amdgcn_mfma_f32_16x16x32_bf16(aHi, bLo, acc[t], 0,0,0);
          acc[t] = __builtin_amdgcn_mfma_f32_16x16x32_bf16(aLo, bHi, acc[t], 0,0,0);
        }
      }
#pragma unroll
      for (int t = 0; t < 8; t++) {
        const int colb = (w*8 + t)*16 + fr;
#pragma unroll
        for (int r = 0; r < 4; r++)
          ysl[(size_t)(kg*4 + r)*2560 + colb] = acc[t][r];
      }
    }
    // ===== phase 1b: y[:, 1024:2560] = X @ {Uxz|Uxr|Uxh}^T (K=256, 12 tiles/wave) =====
    {
      const f32x4 z4 = {0.f,0.f,0.f,0.f};
      f32x4 acc[12];
#pragma unroll
      for (int t = 0; t < 12; t++) acc[t] = z4;
      for (int ki = 0; ki < 8; ki++) {
        const unsigned ao = (unsigned)((fr*512 + ki*64 + kg*16) ^ ((fr & 7) << 4));
        const short8 aHi = *(const short8*)(L + 32768 + ao);
        const short8 aLo = *(const short8*)(L + 40960 + ao);
#pragma unroll
        for (int t = 0; t < 12; t++) {
          const size_t u = 524288 + (size_t)(((w*12 + t)*8 + ki)*512) + lane*8;
          const short8 bHi = *(const short8*)(W0h + u);
          const short8 bLo = *(const short8*)(W0l + u);
          acc[t] = __builtin_amdgcn_mfma_f32_16x16x32_bf16(aHi, bHi, acc[t], 0,0,0);
          acc[t] = __builtin_amdgcn_mfma_f32_16x16x32_bf16(aHi, bLo, acc[t], 0,0,0);
          acc[t] = __builtin_amdgcn_mfma_f32_16x16x32_bf16(aLo, bHi, acc[t], 0,0,0);
        }
      }
#pragma unroll
      for (int t = 0; t < 12; t++) {
        const int colb = 1024 + (w*12 + t)*16 + fr;
#pragma unroll
        for (int r = 0; r < 4; r++)
          ysl[(size_t)(kg*4 + r)*2560 + colb] = acc[t][r];
      }
    }
    __syncthreads();

    // ===== phase 2: gates, wave handles rows w*2, w*2+1 =====
#define PH2_ROW(RI)                                                              \
    {                                                                            \
      const int row = w*2 + (RI);                                                \
      const float* grow = ysl + row * 2560;                                      \
      float h[8], whz[8], whr[8], uxz[8], uxr[8], uxh[8], bz[8], br[8];          \
      _Pragma("unroll")                                                          \
      for (int q = 0; q < 2; q++) {                                              \
        const int j4 = lane + 64*q;                                              \
        const unsigned ho = (unsigned)((row*1024 + j4*8) ^ ((row & 7) << 4));    \
        const ushort4 hh4 = *(const ushort4*)(L + ho);                           \
        const ushort4 hl4 = *(const ushort4*)(L + 16384 + ho);                   \
        const float4 vz  = ((const float4*)grow)[j4];                            \
        const float4 vr  = ((const float4*)(grow + 512))[j4];                    \
        const float4 uz  = ((const float4*)(grow + 1024))[j4];                   \
        const float4 ur  = ((const float4*)(grow + 1536))[j4];                   \
        const float4 uh  = ((const float4*)(grow + 2048))[j4];                   \
        const float4 vbz = ((const float4*)(bb + 1024))[j4];                     \
        const float4 vbr = ((const float4*)bb)[j4];                              \
        _Pragma("unroll")                                                        \
        for (int i = 0; i < 4; i++) {                                            \
          const int e = q*4 + i;                                                 \
          h[e] = bu2f(U4E(hh4,i)) + bu2f(U4E(hl4,i));                            \
          whz[e] = F4E(vz,i); whr[e] = F4E(vr,i);                                \
          uxz[e] = F4E(uz,i); uxr[e] = F4E(ur,i); uxh[e] = F4E(uh,i);            \
          bz[e] = F4E(vbz,i); br[e] = F4E(vbr,i);                               \
        }                                                                        \
      }                                                                          \
      float rh[8];                                                               \
      gate_row(h, whz, whr, uxz, uxr, uxh, bz, br, p_xnx[RI], p_axnx[RI],        \
               rh, pz_[RI], puhx_[RI],                                           \
               p_xnrh[RI], p_axnrh[RI], p_y2u[RI], p_sh2[RI]);                   \
      _Pragma("unroll")                                                          \
      for (int e = 0; e < 8; e++) phh_[RI][e] = h[e];                            \
      _Pragma("unroll")                                                          \
      for (int q = 0; q < 2; q++) {                                              \
        const int j4 = lane + 64*q;                                              \
        const unsigned ro = (unsigned)((row*1024 + j4*8) ^ ((row & 7) << 4));    \
        ushort th[4], tl[4];                                                     \
        _Pragma("unroll")                                                        \
        for (int i = 0; i < 4; i++) split2(rh[q*4+i], th[i], tl[i]);             \
        *(ushort4*)(L + 32768 + ro) = make_ushort4(th[0],th[1],th[2],th[3]);     \
        *(ushort4*)(L + 49152 + ro) = make_ushort4(tl[0],tl[1],tl[2],tl[3]);     \
      }                                                                          \
    }

    PH2_ROW(0)
    PH2_ROW(1)
    __syncthreads();

    // ===== phase 3: htm = RH @ W1^T (K=512, 4 tiles/wave) =====
    {
      const f32x4 z4 = {0.f,0.f,0.f,0.f};
      f32x4 acc[4];
#pragma unroll
      for (int t = 0; t < 4; t++) acc[t] = z4;
      for (int ki = 0; ki < 16; ki++) {
        const unsigned ao = (unsigned)((fr*1024 + ki*64 + kg*16) ^ ((fr & 7) << 4));
        const short8 aHi = *(const short8*)(L + 32768 + ao);
        const short8 aLo = *(const short8*)(L + 49152 + ao);
#pragma unroll
        for (int t = 0; t < 4; t++) {
          const size_t u = (size_t)(((w*4 + t)*16 + ki)*512) + lane*8;
          const short8 bHi = *(const short8*)(W1h + u);
          const short8 bLo = *(const short8*)(W1l + u);
          acc[t] = __builtin_amdgcn_mfma_f32_16x16x32_bf16(aHi, bHi, acc[t], 0,0,0);
          acc[t] = __builtin_amdgcn_mfma_f32_16x16x32_bf16(aHi, bLo, acc[t], 0,0,0);
          acc[t] = __builtin_amdgcn_mfma_f32_16x16x32_bf16(aLo, bHi, acc[t], 0,0,0);
        }
      }
#pragma unroll
      for (int t = 0; t < 4; t++) {
        const int colb = (w*4 + t)*16 + fr;
#pragma unroll
        for (int r = 0; r < 4; r++)
          hsl[(size_t)(kg*4 + r)*512 + colb] = acc[t][r];
      }
    }
    __syncthreads();

    // ===== phase 4: update, wave handles rows w*2, w*2+1; prefetch next x =====
#define PH4_ROW(RI)                                                              \
    {                                                                            \
      const int row = w*2 + (RI);                                                \
      float mt_[8], bh[8];                                                       \
      _Pragma("unroll")                                                          \
      for (int q = 0; q < 2; q++) {                                              \
        const int j4 = lane + 64*q;                                              \
        const float4 vm = ((const float4*)(hsl + row*512))[j4];                  \
        const float4 vb = ((const float4*)(bb + 512))[j4];                       \
        _Pragma("unroll")                                                        \
        for (int i = 0; i < 4; i++) {                                            \
          mt_[q*4+i] = F4E(vm,i); bh[q*4+i] = F4E(vb,i);                         \
        }                                                                        \
      }                                                                          \
      float hnew[8];                                                             \
      update_row(mt_, bh, pz_[RI], puhx_[RI], phh_[RI],                          \
                 p_xnrh[RI], p_axnrh[RI], p_y2u[RI], p_sh2[RI], hnew);           \
      _Pragma("unroll")                                                          \
      for (int q = 0; q < 2; q++) {                                              \
        const int j4 = lane + 64*q;                                              \
        const unsigned ho = (unsigned)((row*1024 + j4*8) ^ ((row & 7) << 4));    \
        ushort th[4], tl[4];                                                     \
        _Pragma("unroll")                                                        \
        for (int i = 0; i < 4; i++) split2(hnew[q*4+i], th[i], tl[i]);           \
        *(ushort4*)(L + ho) = make_ushort4(th[0],th[1],th[2],th[3]);             \
        *(ushort4*)(L + 16384 + ho) = make_ushort4(tl[0],tl[1],tl[2],tl[3]);     \
        if (s == 99)                                                             \
          ((float4*)(hbuf + (size_t)(g*512 + b16*16 + row)*512))[j4] =           \
              make_float4(hnew[q*4], hnew[q*4+1], hnew[q*4+2], hnew[q*4+3]);     \
      }                                                                          \
      if (s + 1 < 100) XLOAD(RI, s + 1)                                          \
    }

    PH4_ROW(0)
    PH4_ROW(1)
    __syncthreads();
  }
}

// ---------- head projection GEMM (f32, runs once; verified rounds 2-3) ----------
__global__ __launch_bounds__(256) void gemm_k(
    const float* __restrict__ hbuf,
    const float* __restrict__ wp_src, const float* __restrict__ wp_tgt,
    const int* __restrict__ alignment,
    float* __restrict__ out)
{
  const int rt = blockIdx.x, ct = blockIdx.y;
  const int rowBase = rt * 64;
  const int tid = threadIdx.x;
  const int chunk = ct >> 2;
  const int colBase = ct * 64, ldo = 512, kdim = 512;
  const float* W = (chunk ? wp_tgt : wp_src) + (size_t)((ct & 3) * 64) * 512;
  const int ar = tid >> 2, ak = (tid & 3) * 4;
  int arow = rowBase + ar;
  if (chunk) arow = 512 + alignment[arow];
  const float* Arow = hbuf + (size_t)arow * kdim;
  const float* Wrow = W + (size_t)(tid >> 2) * kdim + (tid & 3) * 4;

  __shared__ __align__(16) float As[16][68];
  __shared__ __align__(16) float Bs[16][68];
  float acc[4][4] = {{0.f}};
  const int ty = tid >> 4, tx = tid & 15;

  for (int k0 = 0; k0 < kdim; k0 += 16) {
    const float4 av = *(const float4*)(Arow + k0 + ak);
    const float4 bv = *(const float4*)(Wrow + k0);
    const int bj = tid >> 2;
    As[ak + 0][ar] = av.x; As[ak + 1][ar] = av.y; As[ak + 2][ar] = av.z; As[ak + 3][ar] = av.w;
    Bs[ak + 0][bj] = bv.x; Bs[ak + 1][bj] = bv.y; Bs[ak + 2][bj] = bv.z; Bs[ak + 3][bj] = bv.w;
    __syncthreads();
#pragma unroll
    for (int kk = 0; kk < 16; kk++) {
      const float4 a4 = *(const float4*)(&As[kk][ty * 4]);
      const float4 b4 = *(const float4*)(&Bs[kk][tx * 4]);
      acc[0][0] += a4.x * b4.x; acc[0][1] += a4.x * b4.y; acc[0][2] += a4.x * b4.z; acc[0][3] += a4.x * b4.w;
      acc[1][0] += a4.y * b4.x; acc[1][1] += a4.y * b4.y; acc[1][2] += a4.y * b4.z; acc[1][3] += a4.y * b4.w;
      acc[2][0] += a4.z * b4.x; acc[2][1] += a4.z * b4.y; acc[2][2] += a4.z * b4.z; acc[2][3] += a4.z * b4.w;
      acc[3][0] += a4.w * b4.x; acc[3][1] += a4.w * b4.y; acc[3][2] += a4.w * b4.z; acc[3][3] += a4.w * b4.w;
    }
    __syncthreads();
  }
#pragma unroll
  for (int r = 0; r < 4; r++) {
    float4 o; o.x = acc[r][0]; o.y = acc[r][1]; o.z = acc[r][2]; o.w = acc[r][3];
    *(float4*)(out + (size_t)(rowBase + ty * 4 + r) * ldo + colBase + tx * 4) = o;
  }
}

// ---------- head: mobius_linear x2, mobius_add, dist, scalar_mul, dist2plane ----------
template<int N>
__device__ __forceinline__ void block_reduce(float* v) {
  __shared__ float s[4][N];
  __syncthreads();
  const int lane = threadIdx.x & 63;
  const int wv = threadIdx.x >> 6;
#pragma unroll
  for (int n = 0; n < N; n++) {
    float x = v[n];
#pragma unroll
    for (int o = 32; o > 0; o >>= 1) x += __shfl_down(x, o);
    if (lane == 0) s[wv][n] = x;
  }
  __syncthreads();
#pragma unroll
  for (int n = 0; n < N; n++) v[n] = s[0][n] + s[1][n] + s[2][n] + s[3][n];
}

__global__ __launch_bounds__(256) void k_head(
    const float* __restrict__ hb, const float* __restrict__ mxb,
    const float* __restrict__ bp_src, const float* __restrict__ bp_tgt,
    const float* __restrict__ dist_bias, const float* __restrict__ plane_p,
    const float* __restrict__ plane_a, const int* __restrict__ alignment,
    float* __restrict__ outp)
{
  const int b = blockIdx.x;
  const int t = threadIdx.x;
  const int arow = 512 + alignment[b];
  float hs[2], htg[2];
  hs[0] = hb[(size_t)b * 512 + t];      hs[1] = hb[(size_t)b * 512 + 256 + t];
  htg[0] = hb[(size_t)arow * 512 + t];  htg[1] = hb[(size_t)arow * 512 + 256 + t];
  const float mxs = mxb[(size_t)b * 512 + t];
  const float mxt = mxb[(size_t)b * 512 + 256 + t];
  const float bps = bp_src[t], bpt = bp_tgt[t], db = dist_bias[t];
  const float pp0 = plane_p[t], pp1 = plane_p[256 + t];
  const float pa0 = plane_a[t], pa1 = plane_a[256 + t];

  float rA[5] = {0, 0, 0, 0, 0};
#pragma unroll
  for (int e = 0; e < 2; e++) {
    rA[0] += hs[e] * hs[e]; rA[1] += htg[e] * htg[e]; rA[2] += hs[e] * htg[e];
  }
  rA[3] = mxs * mxs; rA[4] = mxt * mxt;
  block_reduce<5>(rA);
  const float shs = rA[0], sht = rA[1], dot_st = rA[2];
  const float xns = sqrtf(fmaxf(shs, EPSF)), axns = artanh_c(xns);
  const float xnt = sqrtf(fmaxf(sht, EPSF)), axnt = artanh_c(xnt);
  const float ms = sqrtf(fmaxf(rA[3], EPSF)); const float ts = tanhf(ms / xns * axns);
  const float ss = (ms <= 1e-7f) ? 0.f : ts / ms; const float x2s = (ms <= 1e-7f) ? 0.f : ts * ts;
  const float mt = sqrtf(fmaxf(rA[4], EPSF)); const float tt = tanhf(mt / xnt * axnt);
  const float st = (mt <= 1e-7f) ? 0.f : tt / mt; const float x2t = (mt <= 1e-7f) ? 0.f : tt * tt;
  const float vs = ss * mxs, vt = st * mxt;

  float rB[5] = {bps * bps, vs * bps, bpt * bpt, vt * bpt, db * db};
  block_reduce<5>(rB);
  float ps, pt;
  {
    const float y2 = rB[0], xy = rB[1];
    const float iv = 1.f / fmaxf(1.f + 2.f * xy + x2s * y2, EPSF);
    ps = ((1.f + 2.f * xy + y2) * vs + (1.f - x2s) * bps) * iv;
  }
  {
    const float y2 = rB[2], xy = rB[3];
    const float iv = 1.f / fmaxf(1.f + 2.f * xy + x2t * y2, EPSF);
    pt = ((1.f + 2.f * xy + y2) * vt + (1.f - x2t) * bpt) * iv;
  }
  float rC[2] = {ps * ps, pt * pt};
  block_reduce<2>(rC);
  {
    const float n = sqrtf(fmaxf(rC[0], EPSF));
    if (n > 0.999f) ps *= 0.999f / n;
  }
  {
    const float n = sqrtf(fmaxf(rC[1], EPSF));
    if (n > 0.999f) pt *= 0.999f / n;
  }
  float df[2];
  {
    const float xy = -dot_st;
    const float iv = 1.f / fmaxf(1.f + 2.f * xy + shs * sht, EPSF);
    const float c1 = 1.f + 2.f * xy + sht, c2 = 1.f - shs;
#pragma unroll
    for (int e = 0; e < 2; e++) df[e] = (c1 * (-hs[e]) + c2 * htg[e]) * iv;
  }
  float rD[4] = {ps * ps, pt * pt, ps * pt, df[0] * df[0] + df[1] * df[1]};
  block_reduce<4>(rD);
  float pr;
  {
    const float x2 = rD[0], y2 = rD[1], xy = rD[2];
    const float iv = 1.f / fmaxf(1.f + 2.f * xy + x2 * y2, EPSF);
    pr = ((1.f + 2.f * xy + y2) * ps + (1.f - x2) * pt) * iv;
  }
  const float dn = sqrtf(fmaxf(rD[3], EPSF));
  const float dist = 2.f * artanh_c(dn);
  const float d2v = dist * dist;
  const float dbn = sqrtf(fmaxf(rB[4], EPSF));
  const float biasv = tanhf(d2v * artanh_c(dbn)) * db / dbn;

  float rE[3] = {pr * pr, biasv * biasv, pr * biasv};
  block_reduce<3>(rE);
  float pr2;
  {
    const float x2 = rE[0], y2 = rE[1], xy = rE[2];
    const float iv = 1.f / fmaxf(1.f + 2.f * xy + x2 * y2, EPSF);
    pr2 = ((1.f + 2.f * xy + y2) * pr + (1.f - x2) * biasv) * iv;
  }
  float rF[5] = {pp0 * pp0, pp0 * pr2, pp1 * pp1, pp1 * pr2, pr2 * pr2};
  block_reduce<5>(rF);
  float d0, d1;
  {
    const float x2 = rF[0], xy = -rF[1], y2 = rF[4];
    const float iv = 1.f / fmaxf(1.f + 2.f * xy + x2 * y2, EPSF);
    d0 = ((1.f + 2.f * xy + y2) * (-pp0) + (1.f - x2) * pr2) * iv;
  }
  {
    const float x2 = rF[2], xy = -rF[3], y2 = rF[4];
    const float iv = 1.f / fmaxf(1.f + 2.f * xy + x2 * y2, EPSF);
    d1 = ((1.f + 2.f * xy + y2) * (-pp1) + (1.f - x2) * pr2) * iv;
  }
  float rG[6] = {d0 * d0, d0 * pa0, pa0 * pa0, d1 * d1, d1 * pa1, pa1 * pa1};
  block_reduce<6>(rG);
  if (t == 0) {
    const float an0 = sqrtf(fmaxf(rG[2], EPSF));
    const float an1 = sqrtf(fmaxf(rG[5], EPSF));
    outp[b * 2 + 0] = asinhf(2.f * rG[1] / fmaxf((1.f - rG[0]) * an0, EPSF));
    outp[b * 2 + 1] = asinhf(2.f * rG[4] / fmaxf((1.f - rG[3]) * an1, EPSF));
  }
}

// ---------- launch ----------
extern "C" void kernel_launch(void* const* d_in, const int* in_sizes, int n_in,
                              void* d_out, int out_size, void* d_ws, size_t ws_size,
                              hipStream_t stream) {
  const float* emb       = (const float*)d_in[0];
  const float* w_ih_src  = (const float*)d_in[1];
  const float* w_hh_src  = (const float*)d_in[2];
  const float* b_src     = (const float*)d_in[3];
  const float* w_ih_tgt  = (const float*)d_in[4];
  const float* w_hh_tgt  = (const float*)d_in[5];
  const float* b_tgt     = (const float*)d_in[6];
  const float* wp_src    = (const float*)d_in[7];
  const float* bp_src    = (const float*)d_in[8];
  const float* wp_tgt    = (const float*)d_in[9];
  const float* bp_tgt    = (const float*)d_in[10];
  const float* dist_bias = (const float*)d_in[11];
  const float* plane_p   = (const float*)d_in[12];
  const float* plane_a   = (const float*)d_in[13];
  const int* src_t       = (const int*)d_in[14];
  const int* tgt_t       = (const int*)d_in[15];
  const int* alignment   = (const int*)d_in[16];
  float* outp            = (float*)d_out;

  char* wsb = (char*)d_ws;
  float* yws   = (float*)(wsb + 0);          // 64 x [16][2560] f32 = 10.5 MB
  float* htmws = (float*)(wsb + 10485760);   // 64 x [16][512]  f32 = 2 MB
  float* hbuf  = (float*)(wsb + 12582912);   // [1024][512] f32 = 2 MB
  float* mxb   = (float*)(wsb + 14680064);   // [512][512]  f32 = 1 MB
  bf16*  W0h   = (bf16*)(wsb + 15728640);    // 1835008
  bf16*  W0l   = (bf16*)(wsb + 19398656);
  bf16*  W1h   = (bf16*)(wsb + 23068672);    // 524288
  bf16*  W1l   = (bf16*)(wsb + 24117248);    // end 25165824 (~25 MB)

  k_wconv<<<9216, 256, 0, stream>>>(w_ih_src, w_hh_src, w_ih_tgt, w_hh_tgt,
                                    W0h, W0l, W1h, W1l);
  k_rnn<<<64, 512, 0, stream>>>(emb, src_t, tgt_t, b_src, b_tgt,
                                W0h, W0l, W1h, W1l, yws, htmws, hbuf);
  gemm_k<<<dim3(8, 8), 256, 0, stream>>>(hbuf, wp_src, wp_tgt, alignment, mxb);
  k_head<<<512, 256, 0, stream>>>(hbuf, mxb, bp_src, bp_tgt, dist_bias,
                                  plane_p, plane_a, alignment, outp);
}

// Round 6
// 8191.050 us; speedup vs baseline: 2.2746x; 1.9155x over previous
//
#include <hip/hip_runtime.h>
#include <hip/hip_bf16.h>

#define EPSF 1e-15f

typedef __hip_bfloat16 bf16;
typedef __attribute__((ext_vector_type(8))) short short8;
typedef __attribute__((ext_vector_type(4))) float f32x4;

#define F4E(v,i) ((i)==0?(v).x:((i)==1?(v).y:((i)==2?(v).z:(v).w)))
#define U4E(v,i) ((i)==0?(v).x:((i)==1?(v).y:((i)==2?(v).z:(v).w)))

// ---------- helpers ----------
__device__ __forceinline__ float artanh_c(float x) {
  x = fminf(fmaxf(x, -1.f + 1e-5f), 1.f - 1e-5f);
  return 0.5f * log1pf(2.f * x / (1.f - x));
}
__device__ __forceinline__ float sigmoidf(float x) { return 1.f / (1.f + expf(-x)); }
__device__ __forceinline__ float wave_sum(float x) {
#pragma unroll
  for (int o = 32; o > 0; o >>= 1) x += __shfl_xor(x, o);
  return x;
}
__device__ __forceinline__ float bu2f(ushort u) { return __uint_as_float(((unsigned)u) << 16); }
__device__ __forceinline__ ushort f2bu(float v) {
  bf16 t = __float2bfloat16(v);
  union { bf16 b; ushort u; } c; c.b = t; return c.u;
}
__device__ __forceinline__ void split2(float v, ushort& h, ushort& l) {
  h = f2bu(v); l = f2bu(v - bu2f(h));
}

// ---------- weight packing: fragment-major bf16 (hi plane only; once per call) ----------
// W0 per GRU (917504): h-part (cols 0-1023 = Whz|Whr, K=512) then x-part
// (cols 0-1535 = Uxz|Uxr|Uxh, K=256). Packed unit = (col-tile, ki): 64 lanes x 8 shorts,
// lane l covers col=ct*16+(l&15), k=ki*32+(l>>4)*8.. -> wave B-frag load = 1KB coalesced.
__global__ __launch_bounds__(256) void k_wconv(
    const float* __restrict__ w_ih_src, const float* __restrict__ w_hh_src,
    const float* __restrict__ w_ih_tgt, const float* __restrict__ w_hh_tgt,
    bf16* __restrict__ W0h, bf16* __restrict__ W1h)
{
  const int idx = blockIdx.x * 256 + threadIdx.x;   // 2359296 total
  float v;
  if (idx < 1835008) {
    const int g = idx / 917504, p = idx % 917504;
    const float* wih = g ? w_ih_tgt : w_ih_src;
    const float* whh = g ? w_hh_tgt : w_hh_src;
    if (p < 524288) {                 // h-part, K=512
      const int unit = p >> 9, r = p & 511, lane = r >> 3, e = r & 7;
      const int ct = unit >> 4, ki = unit & 15;
      const int col = ct*16 + (lane & 15), k = ki*32 + (lane >> 4)*8 + e;
      v = (col < 512) ? whh[524288 + col*512 + k]      // Whz = w_hh[2]
                      : whh[(col - 512)*512 + k];      // Whr = w_hh[0]
    } else {                          // x-part, K=256
      const int q = p - 524288;
      const int unit = q >> 9, r = q & 511, lane = r >> 3, e = r & 7;
      const int ct = unit >> 3, ki = unit & 7;
      const int col = ct*16 + (lane & 15), k = ki*32 + (lane >> 4)*8 + e;
      v = (col < 512)  ? wih[262144 + col*256 + k]           // Uxz = w_ih[2]
        : (col < 1024) ? wih[(col - 512)*256 + k]            // Uxr = w_ih[0]
                       : wih[131072 + (col - 1024)*256 + k]; // Uxh = w_ih[1]
    }
    ((ushort*)W0h)[idx] = f2bu(v);
  } else {
    const int j = idx - 1835008;
    if (j >= 524288) return;
    const int g = j >> 18, p = j & 262143;
    const float* whh = g ? w_hh_tgt : w_hh_src;
    const int unit = p >> 9, r = p & 511, lane = r >> 3, e = r & 7;
    const int ct = unit >> 4, ki = unit & 15;
    const int col = ct*16 + (lane & 15), k = ki*32 + (lane >> 4)*8 + e;
    v = whh[262144 + col*512 + k];                     // W_hh_ = w_hh[1]
    ((ushort*)W1h)[j] = f2bu(v);
  }
}

// ---------- row-local gate math (pure registers; verified rounds 2-5) ----------
__device__ __forceinline__ void gate_row(
    const float h[8], const float whz[8], const float whr[8],
    const float uxz[8], const float uxr[8], const float uxh[8],
    const float bz[8], const float br[8],
    float xn_x, float axn_x,
    float rh[8], float pz[8], float puhx[8],
    float& o_xnrh, float& o_axnrh, float& o_y2u, float& o_sh2)
{
  float r60=0, r61=0, r62=0, r63=0, r64_=0, r65=0;
#pragma unroll
  for (int e = 0; e < 8; e++) {
    r60 += h[e]*h[e];     r61 += whz[e]*whz[e]; r62 += whr[e]*whr[e];
    r63 += uxz[e]*uxz[e]; r64_ += uxr[e]*uxr[e]; r65 += uxh[e]*uxh[e];
  }
  r60 = wave_sum(r60); r61 = wave_sum(r61); r62 = wave_sum(r62);
  r63 = wave_sum(r63); r64_ = wave_sum(r64_); r65 = wave_sum(r65);
  const float sh2 = r60;
  const float xn_h = sqrtf(fmaxf(sh2, EPSF)), axn_h = artanh_c(xn_h);
  const float mz = sqrtf(fmaxf(r61, EPSF)); const float tz = tanhf(mz / xn_h * axn_h);
  const float sz = (mz <= 1e-7f) ? 0.f : tz/mz; const float x2z = (mz <= 1e-7f) ? 0.f : tz*tz;
  const float mr = sqrtf(fmaxf(r62, EPSF)); const float tr_ = tanhf(mr / xn_h * axn_h);
  const float sr = (mr <= 1e-7f) ? 0.f : tr_/mr; const float x2r = (mr <= 1e-7f) ? 0.f : tr_*tr_;
  const float muz = sqrtf(fmaxf(r63, EPSF)); const float tuz = tanhf(muz / xn_x * axn_x);
  const float suz = (muz <= 1e-7f) ? 0.f : tuz/muz; const float y2z = (muz <= 1e-7f) ? 0.f : tuz*tuz;
  const float mur = sqrtf(fmaxf(r64_, EPSF)); const float tur = tanhf(mur / xn_x * axn_x);
  const float sur = (mur <= 1e-7f) ? 0.f : tur/mur; const float y2r = (mur <= 1e-7f) ? 0.f : tur*tur;
  const float muh = sqrtf(fmaxf(r65, EPSF)); const float tuh = tanhf(muh / xn_x * axn_x);
  const float suh = (muh <= 1e-7f) ? 0.f : tuh/muh; const float y2u = (muh <= 1e-7f) ? 0.f : tuh*tuh;

  float dd0 = 0, dd1 = 0;
#pragma unroll
  for (int e = 0; e < 8; e++) {
    dd0 += (sz*whz[e])*(suz*uxz[e]);
    dd1 += (sr*whr[e])*(sur*uxr[e]);
  }
  dd0 = wave_sum(dd0); dd1 = wave_sum(dd1);
  float t1z[8], t1r[8];
  {
    const float iv = 1.f / fmaxf(1.f + 2.f*dd0 + x2z*y2z, EPSF);
    const float c1 = 1.f + 2.f*dd0 + y2z, c2 = 1.f - x2z;
#pragma unroll
    for (int e = 0; e < 8; e++) t1z[e] = (c1*(sz*whz[e]) + c2*(suz*uxz[e])) * iv;
  }
  {
    const float iv = 1.f / fmaxf(1.f + 2.f*dd1 + x2r*y2r, EPSF);
    const float c1 = 1.f + 2.f*dd1 + y2r, c2 = 1.f - x2r;
#pragma unroll
    for (int e = 0; e < 8; e++) t1r[e] = (c1*(sr*whr[e]) + c2*(sur*uxr[e])) * iv;
  }
  float e0=0, e1=0, e2=0, e3=0, e4=0, e5=0;
#pragma unroll
  for (int e = 0; e < 8; e++) {
    e0 += t1z[e]*t1z[e]; e1 += t1z[e]*bz[e]; e2 += bz[e]*bz[e];
    e3 += t1r[e]*t1r[e]; e4 += t1r[e]*br[e]; e5 += br[e]*br[e];
  }
  e0 = wave_sum(e0); e1 = wave_sum(e1); e2 = wave_sum(e2);
  e3 = wave_sum(e3); e4 = wave_sum(e4); e5 = wave_sum(e5);
  float t2z[8], t2r[8];
  {
    const float iv = 1.f / fmaxf(1.f + 2.f*e1 + e0*e2, EPSF);
    const float c1 = 1.f + 2.f*e1 + e2, c2 = 1.f - e0;
#pragma unroll
    for (int e = 0; e < 8; e++) t2z[e] = (c1*t1z[e] + c2*bz[e]) * iv;
  }
  {
    const float iv = 1.f / fmaxf(1.f + 2.f*e4 + e3*e5, EPSF);
    const float c1 = 1.f + 2.f*e4 + e5, c2 = 1.f - e3;
#pragma unroll
    for (int e = 0; e < 8; e++) t2r[e] = (c1*t1r[e] + c2*br[e]) * iv;
  }
  float n0 = 0, n1 = 0;
#pragma unroll
  for (int e = 0; e < 8; e++) { n0 += t2z[e]*t2z[e]; n1 += t2r[e]*t2r[e]; }
  n0 = wave_sum(n0); n1 = wave_sum(n1);
  const float nz = sqrtf(fmaxf(n0, EPSF)); const float fz = artanh_c(nz) / nz;
  const float nr = sqrtf(fmaxf(n1, EPSF)); const float frg = artanh_c(nr) / nr;
  float wx[8];
  float rw = 0;
#pragma unroll
  for (int e = 0; e < 8; e++) {
    pz[e] = sigmoidf(fz * t2z[e]);
    const float rr = sigmoidf(frg * t2r[e]);
    wx[e] = rr * h[e];
    rw += wx[e]*wx[e];
  }
  rw = wave_sum(rw);
  const float wxn = sqrtf(fmaxf(rw, EPSF));
  const float trh = tanhf(wxn / xn_h * axn_h);
  const float srh = (wxn <= 1e-7f) ? 0.f : trh / wxn;
  const float xn_rh = (wxn <= 1e-7f) ? sqrtf(EPSF) : fmaxf(trh, sqrtf(EPSF));
#pragma unroll
  for (int e = 0; e < 8; e++) { rh[e] = srh * wx[e]; puhx[e] = suh * uxh[e]; }
  o_xnrh = xn_rh; o_axnrh = artanh_c(xn_rh); o_y2u = y2u; o_sh2 = sh2;
}

// ---------- row-local update math ----------
__device__ __forceinline__ void update_row(
    const float mt_[8], const float bh[8],
    const float pz[8], const float puhx[8], const float phv[8],
    float p_xnrh, float p_axnrh, float p_y2u, float p_sh2,
    float hnew[8])
{
  float a0s = 0, a1s = 0;
#pragma unroll
  for (int e = 0; e < 8; e++) { a0s += mt_[e]*mt_[e]; a1s += mt_[e]*puhx[e]; }
  a0s = wave_sum(a0s); a1s = wave_sum(a1s);
  const float m = sqrtf(fmaxf(a0s, EPSF));
  const float tt = tanhf(m / p_xnrh * p_axnrh);
  const float st = (m <= 1e-7f) ? 0.f : tt/m;
  const float x2 = (m <= 1e-7f) ? 0.f : tt*tt;
  float t1[8];
  {
    const float xy = st * a1s;
    const float iv = 1.f / fmaxf(1.f + 2.f*xy + x2*p_y2u, EPSF);
    const float c1 = 1.f + 2.f*xy + p_y2u, c2 = 1.f - x2;
#pragma unroll
    for (int e = 0; e < 8; e++) t1[e] = (c1*(st*mt_[e]) + c2*puhx[e]) * iv;
  }
  float b0s = 0, b1s = 0, b2s = 0;
#pragma unroll
  for (int e = 0; e < 8; e++) { b0s += t1[e]*t1[e]; b1s += t1[e]*bh[e]; b2s += bh[e]*bh[e]; }
  b0s = wave_sum(b0s); b1s = wave_sum(b1s); b2s = wave_sum(b2s);
  float ht[8];
  {
    const float iv = 1.f / fmaxf(1.f + 2.f*b1s + b0s*b2s, EPSF);
    const float c1 = 1.f + 2.f*b1s + b2s, c2 = 1.f - b0s;
#pragma unroll
    for (int e = 0; e < 8; e++) ht[e] = (c1*t1[e] + c2*bh[e]) * iv;
  }
  float c0s = 0, c1s = 0;
#pragma unroll
  for (int e = 0; e < 8; e++) { c0s += ht[e]*ht[e]; c1s += phv[e]*ht[e]; }
  c0s = wave_sum(c0s); c1s = wave_sum(c1s);
  float delta[8];
  {
    const float xy = -c1s;
    const float iv = 1.f / fmaxf(1.f + 2.f*xy + p_sh2*c0s, EPSF);
    const float c1 = 1.f + 2.f*xy + c0s, c2 = 1.f - p_sh2;
#pragma unroll
    for (int e = 0; e < 8; e++) delta[e] = (c1*(-phv[e]) + c2*ht[e]) * iv;
  }
  float d0s = 0, d1s = 0, d2s = 0;
#pragma unroll
  for (int e = 0; e < 8; e++) {
    const float ww = pz[e]*delta[e];
    d0s += delta[e]*delta[e]; d1s += ww*ww; d2s += phv[e]*ww;
  }
  d0s = wave_sum(d0s); d1s = wave_sum(d1s); d2s = wave_sum(d2s);
  const float dn = sqrtf(fmaxf(d0s, EPSF));
  const float axnd = artanh_c(dn);
  const float wxn = sqrtf(fmaxf(d1s, EPSF));
  const float tzd = tanhf(wxn / dn * axnd);
  const float szd = (wxn <= 1e-7f) ? 0.f : tzd/wxn;
  const float y2zd = (wxn <= 1e-7f) ? 0.f : tzd*tzd;
  const float xy = szd * d2s;
  const float iv = 1.f / fmaxf(1.f + 2.f*xy + p_sh2*y2zd, EPSF);
  const float c1 = 1.f + 2.f*xy + y2zd, c2 = 1.f - p_sh2;
#pragma unroll
  for (int e = 0; e < 8; e++) hnew[e] = (c1*phv[e] + c2*(szd*pz[e]*delta[e])) * iv;
}

// ---------- the row-local persistent RNN kernel: 64 blocks x 16 rows, no grid sync ----------
// Weights: bf16 hi-plane only (2-product split on activations). XCD-pure GRU partition:
// xcd=bid&7 -> g=xcd>>2 (bid%8 is the empirical XCD map; correctness doesn't depend on it,
// only L2 locality). Per-XCD weight set = 2.35 MB < 4 MB L2 -> L2-resident after step 0.
// LDS map (64KB): [0,16K)=H_hi [16K,32K)=H_lo; M=[32K,64K): ph1 x_hi@32K x_lo@40K;
// ph2-3 rh_hi@32K rh_lo@48K. XOR swizzle byte^=((row&7)<<4) on all act planes.
__global__ __launch_bounds__(512, 1) void k_rnn(
    const float* __restrict__ emb, const int* __restrict__ src_t,
    const int* __restrict__ tgt_t, const float* __restrict__ b_src,
    const float* __restrict__ b_tgt,
    const bf16* __restrict__ W0h_, const bf16* __restrict__ W1h_,
    float* __restrict__ yws, float* __restrict__ htmws,
    float* __restrict__ hbuf)
{
  const int bid = blockIdx.x, tid = threadIdx.x;
  const int w = tid >> 6, lane = tid & 63;
  const int fr = lane & 15, kg = lane >> 4;
  const int xcd = bid & 7, slot = bid >> 3;
  const int g = xcd >> 2;                    // XCDs 0-3 -> GRU0, 4-7 -> GRU1
  const int b16 = (xcd & 3) * 8 + slot;      // 0..31 within GRU
  const bf16* W0h = W0h_ + (size_t)g * 917504;
  const bf16* W1h = W1h_ + (size_t)g * 262144;
  const int* toks = g ? tgt_t : src_t;
  const float* bb = g ? b_tgt : b_src;
  float* ysl = yws + (size_t)bid * 40960;    // [16][2560] f32, block-private
  float* hsl = htmws + (size_t)bid * 8192;   // [16][512]  f32, block-private

  __shared__ char L[65536];
  for (int i = tid; i < 2048; i += 512) ((float4*)L)[i] = make_float4(0.f,0.f,0.f,0.f);

  float p_xnx[2], p_axnx[2];
  float pz_[2][8], puhx_[2][8], phh_[2][8];
  float p_xnrh[2], p_axnrh[2], p_y2u[2], p_sh2[2];

#define XLOAD(RI, TOKIDX)                                                        \
  {                                                                              \
    const int row = w*2 + (RI);                                                  \
    const int tok = toks[(b16*16 + row)*100 + (TOKIDX)];                         \
    const float4 ev = ((const float4*)(emb + (size_t)tok * 256))[lane];          \
    float ss = ev.x*ev.x + ev.y*ev.y + ev.z*ev.z + ev.w*ev.w;                    \
    ss = wave_sum(ss);                                                           \
    const float un = sqrtf(fmaxf(ss, EPSF));                                     \
    const float fac = tanhf(un) / un;                                            \
    const float xnv = sqrtf(fmaxf(fac*fac*ss, EPSF));                            \
    p_xnx[RI] = xnv; p_axnx[RI] = artanh_c(xnv);                                 \
    ushort th[4], tl[4];                                                         \
    split2(fac*ev.x, th[0], tl[0]); split2(fac*ev.y, th[1], tl[1]);              \
    split2(fac*ev.z, th[2], tl[2]); split2(fac*ev.w, th[3], tl[3]);              \
    const unsigned xo = (unsigned)((row*512 + lane*8) ^ ((row & 7) << 4));       \
    *(ushort4*)(L + 32768 + xo) = make_ushort4(th[0],th[1],th[2],th[3]);         \
    *(ushort4*)(L + 40960 + xo) = make_ushort4(tl[0],tl[1],tl[2],tl[3]);         \
  }

  XLOAD(0, 0)
  XLOAD(1, 0)
  __syncthreads();

  for (int s = 0; s < 100; s++) {
    // ===== phase 1a: y[:, 0:1024] = H @ {Whz|Whr}^T (K=512, 8 tiles/wave, 2-product) =====
    {
      const f32x4 z4 = {0.f,0.f,0.f,0.f};
      f32x4 acc[8];
#pragma unroll
      for (int t = 0; t < 8; t++) acc[t] = z4;
#pragma unroll 2
      for (int ki = 0; ki < 16; ki++) {
        short8 bfr[8];
#pragma unroll
        for (int t = 0; t < 8; t++)
          bfr[t] = *(const short8*)(W0h + (size_t)(((w*8 + t)*16 + ki)*512) + lane*8);
        const unsigned ao = (unsigned)((fr*1024 + ki*64 + kg*16) ^ ((fr & 7) << 4));
        const short8 aHi = *(const short8*)(L + ao);
        const short8 aLo = *(const short8*)(L + 16384 + ao);
#pragma unroll
        for (int t = 0; t < 8; t++) {
          acc[t] = __builtin_amdgcn_mfma_f32_16x16x32_bf16(aHi, bfr[t], acc[t], 0,0,0);
          acc[t] = __builtin_amdgcn_mfma_f32_16x16x32_bf16(aLo, bfr[t], acc[t], 0,0,0);
        }
      }
#pragma unroll
      for (int t = 0; t < 8; t++) {
        const int colb = (w*8 + t)*16 + fr;
#pragma unroll
        for (int r = 0; r < 4; r++)
          ysl[(size_t)(kg*4 + r)*2560 + colb] = acc[t][r];
      }
    }
    // ===== phase 1b: y[:, 1024:2560] = X @ {Uxz|Uxr|Uxh}^T (K=256, 12 tiles/wave) =====
    {
      const f32x4 z4 = {0.f,0.f,0.f,0.f};
      f32x4 acc[12];
#pragma unroll
      for (int t = 0; t < 12; t++) acc[t] = z4;
      for (int ki = 0; ki < 8; ki++) {
        short8 bfr[12];
#pragma unroll
        for (int t = 0; t < 12; t++)
          bfr[t] = *(const short8*)(W0h + 524288 + (size_t)(((w*12 + t)*8 + ki)*512) + lane*8);
        const unsigned ao = (unsigned)((fr*512 + ki*64 + kg*16) ^ ((fr & 7) << 4));
        const short8 aHi = *(const short8*)(L + 32768 + ao);
        const short8 aLo = *(const short8*)(L + 40960 + ao);
#pragma unroll
        for (int t = 0; t < 12; t++) {
          acc[t] = __builtin_amdgcn_mfma_f32_16x16x32_bf16(aHi, bfr[t], acc[t], 0,0,0);
          acc[t] = __builtin_amdgcn_mfma_f32_16x16x32_bf16(aLo, bfr[t], acc[t], 0,0,0);
        }
      }
#pragma unroll
      for (int t = 0; t < 12; t++) {
        const int colb = 1024 + (w*12 + t)*16 + fr;
#pragma unroll
        for (int r = 0; r < 4; r++)
          ysl[(size_t)(kg*4 + r)*2560 + colb] = acc[t][r];
      }
    }
    __syncthreads();

    // ===== phase 2: gates, wave handles rows w*2, w*2+1 =====
#define PH2_ROW(RI)                                                              \
    {                                                                            \
      const int row = w*2 + (RI);                                                \
      const float* grow = ysl + row * 2560;                                      \
      float h[8], whz[8], whr[8], uxz[8], uxr[8], uxh[8], bz[8], br[8];          \
      _Pragma("unroll")                                                          \
      for (int q = 0; q < 2; q++) {                                              \
        const int j4 = lane + 64*q;                                              \
        const unsigned ho = (unsigned)((row*1024 + j4*8) ^ ((row & 7) << 4));    \
        const ushort4 hh4 = *(const ushort4*)(L + ho);                           \
        const ushort4 hl4 = *(const ushort4*)(L + 16384 + ho);                   \
        const float4 vz  = ((const float4*)grow)[j4];                            \
        const float4 vr  = ((const float4*)(grow + 512))[j4];                    \
        const float4 uz  = ((const float4*)(grow + 1024))[j4];                   \
        const float4 ur  = ((const float4*)(grow + 1536))[j4];                   \
        const float4 uh  = ((const float4*)(grow + 2048))[j4];                   \
        const float4 vbz = ((const float4*)(bb + 1024))[j4];                     \
        const float4 vbr = ((const float4*)bb)[j4];                              \
        _Pragma("unroll")                                                        \
        for (int i = 0; i < 4; i++) {                                            \
          const int e = q*4 + i;                                                 \
          h[e] = bu2f(U4E(hh4,i)) + bu2f(U4E(hl4,i));                            \
          whz[e] = F4E(vz,i); whr[e] = F4E(vr,i);                                \
          uxz[e] = F4E(uz,i); uxr[e] = F4E(ur,i); uxh[e] = F4E(uh,i);            \
          bz[e] = F4E(vbz,i); br[e] = F4E(vbr,i);                               \
        }                                                                        \
      }                                                                          \
      float rh[8];                                                               \
      gate_row(h, whz, whr, uxz, uxr, uxh, bz, br, p_xnx[RI], p_axnx[RI],        \
               rh, pz_[RI], puhx_[RI],                                           \
               p_xnrh[RI], p_axnrh[RI], p_y2u[RI], p_sh2[RI]);                   \
      _Pragma("unroll")                                                          \
      for (int e = 0; e < 8; e++) phh_[RI][e] = h[e];                            \
      _Pragma("unroll")                                                          \
      for (int q = 0; q < 2; q++) {                                              \
        const int j4 = lane + 64*q;                                              \
        const unsigned ro = (unsigned)((row*1024 + j4*8) ^ ((row & 7) << 4));    \
        ushort th[4], tl[4];                                                     \
        _Pragma("unroll")                                                        \
        for (int i = 0; i < 4; i++) split2(rh[q*4+i], th[i], tl[i]);             \
        *(ushort4*)(L + 32768 + ro) = make_ushort4(th[0],th[1],th[2],th[3]);     \
        *(ushort4*)(L + 49152 + ro) = make_ushort4(tl[0],tl[1],tl[2],tl[3]);     \
      }                                                                          \
    }

    PH2_ROW(0)
    PH2_ROW(1)
    __syncthreads();

    // ===== phase 3: htm = RH @ W1^T (K=512, 4 tiles/wave) =====
    {
      const f32x4 z4 = {0.f,0.f,0.f,0.f};
      f32x4 acc[4];
#pragma unroll
      for (int t = 0; t < 4; t++) acc[t] = z4;
#pragma unroll 2
      for (int ki = 0; ki < 16; ki++) {
        short8 bfr[4];
#pragma unroll
        for (int t = 0; t < 4; t++)
          bfr[t] = *(const short8*)(W1h + (size_t)(((w*4 + t)*16 + ki)*512) + lane*8);
        const unsigned ao = (unsigned)((fr*1024 + ki*64 + kg*16) ^ ((fr & 7) << 4));
        const short8 aHi = *(const short8*)(L + 32768 + ao);
        const short8 aLo = *(const short8*)(L + 49152 + ao);
#pragma unroll
        for (int t = 0; t < 4; t++) {
          acc[t] = __builtin_amdgcn_mfma_f32_16x16x32_bf16(aHi, bfr[t], acc[t], 0,0,0);
          acc[t] = __builtin_amdgcn_mfma_f32_16x16x32_bf16(aLo, bfr[t], acc[t], 0,0,0);
        }
      }
#pragma unroll
      for (int t = 0; t < 4; t++) {
        const int colb = (w*4 + t)*16 + fr;
#pragma unroll
        for (int r = 0; r < 4; r++)
          hsl[(size_t)(kg*4 + r)*512 + colb] = acc[t][r];
      }
    }
    __syncthreads();

    // ===== phase 4: update, wave handles rows w*2, w*2+1; prefetch next x =====
#define PH4_ROW(RI)                                                              \
    {                                                                            \
      const int row = w*2 + (RI);                                                \
      float mt_[8], bh[8];                                                       \
      _Pragma("unroll")                                                          \
      for (int q = 0; q < 2; q++) {                                              \
        const int j4 = lane + 64*q;                                              \
        const float4 vm = ((const float4*)(hsl + row*512))[j4];                  \
        const float4 vb = ((const float4*)(bb + 512))[j4];                       \
        _Pragma("unroll")                                                        \
        for (int i = 0; i < 4; i++) {                                            \
          mt_[q*4+i] = F4E(vm,i); bh[q*4+i] = F4E(vb,i);                         \
        }                                                                        \
      }                                                                          \
      float hnew[8];                                                             \
      update_row(mt_, bh, pz_[RI], puhx_[RI], phh_[RI],                          \
                 p_xnrh[RI], p_axnrh[RI], p_y2u[RI], p_sh2[RI], hnew);           \
      _Pragma("unroll")                                                          \
      for (int q = 0; q < 2; q++) {                                              \
        const int j4 = lane + 64*q;                                              \
        const unsigned ho = (unsigned)((row*1024 + j4*8) ^ ((row & 7) << 4));    \
        ushort th[4], tl[4];                                                     \
        _Pragma("unroll")                                                        \
        for (int i = 0; i < 4; i++) split2(hnew[q*4+i], th[i], tl[i]);           \
        *(ushort4*)(L + ho) = make_ushort4(th[0],th[1],th[2],th[3]);             \
        *(ushort4*)(L + 16384 + ho) = make_ushort4(tl[0],tl[1],tl[2],tl[3]);     \
        if (s == 99)                                                             \
          ((float4*)(hbuf + (size_t)(g*512 + b16*16 + row)*512))[j4] =           \
              make_float4(hnew[q*4], hnew[q*4+1], hnew[q*4+2], hnew[q*4+3]);     \
      }                                                                          \
      if (s + 1 < 100) XLOAD(RI, s + 1)                                          \
    }

    PH4_ROW(0)
    PH4_ROW(1)
    __syncthreads();
  }
}

// ---------- head projection GEMM (f32, runs once; verified rounds 2-5) ----------
__global__ __launch_bounds__(256) void gemm_k(
    const float* __restrict__ hbuf,
    const float* __restrict__ wp_src, const float* __restrict__ wp_tgt,
    const int* __restrict__ alignment,
    float* __restrict__ out)
{
  const int rt = blockIdx.x, ct = blockIdx.y;
  const int rowBase = rt * 64;
  const int tid = threadIdx.x;
  const int chunk = ct >> 2;
  const int colBase = ct * 64, ldo = 512, kdim = 512;
  const float* W = (chunk ? wp_tgt : wp_src) + (size_t)((ct & 3) * 64) * 512;
  const int ar = tid >> 2, ak = (tid & 3) * 4;
  int arow = rowBase + ar;
  if (chunk) arow = 512 + alignment[arow];
  const float* Arow = hbuf + (size_t)arow * kdim;
  const float* Wrow = W + (size_t)(tid >> 2) * kdim + (tid & 3) * 4;

  __shared__ __align__(16) float As[16][68];
  __shared__ __align__(16) float Bs[16][68];
  float acc[4][4] = {{0.f}};
  const int ty = tid >> 4, tx = tid & 15;

  for (int k0 = 0; k0 < kdim; k0 += 16) {
    const float4 av = *(const float4*)(Arow + k0 + ak);
    const float4 bv = *(const float4*)(Wrow + k0);
    const int bj = tid >> 2;
    As[ak + 0][ar] = av.x; As[ak + 1][ar] = av.y; As[ak + 2][ar] = av.z; As[ak + 3][ar] = av.w;
    Bs[ak + 0][bj] = bv.x; Bs[ak + 1][bj] = bv.y; Bs[ak + 2][bj] = bv.z; Bs[ak + 3][bj] = bv.w;
    __syncthreads();
#pragma unroll
    for (int kk = 0; kk < 16; kk++) {
      const float4 a4 = *(const float4*)(&As[kk][ty * 4]);
      const float4 b4 = *(const float4*)(&Bs[kk][tx * 4]);
      acc[0][0] += a4.x * b4.x; acc[0][1] += a4.x * b4.y; acc[0][2] += a4.x * b4.z; acc[0][3] += a4.x * b4.w;
      acc[1][0] += a4.y * b4.x; acc[1][1] += a4.y * b4.y; acc[1][2] += a4.y * b4.z; acc[1][3] += a4.y * b4.w;
      acc[2][0] += a4.z * b4.x; acc[2][1] += a4.z * b4.y; acc[2][2] += a4.z * b4.z; acc[2][3] += a4.z * b4.w;
      acc[3][0] += a4.w * b4.x; acc[3][1] += a4.w * b4.y; acc[3][2] += a4.w * b4.z; acc[3][3] += a4.w * b4.w;
    }
    __syncthreads();
  }
#pragma unroll
  for (int r = 0; r < 4; r++) {
    float4 o; o.x = acc[r][0]; o.y = acc[r][1]; o.z = acc[r][2]; o.w = acc[r][3];
    *(float4*)(out + (size_t)(rowBase + ty * 4 + r) * ldo + colBase + tx * 4) = o;
  }
}

// ---------- head ----------
template<int N>
__device__ __forceinline__ void block_reduce(float* v) {
  __shared__ float s[4][N];
  __syncthreads();
  const int lane = threadIdx.x & 63;
  const int wv = threadIdx.x >> 6;
#pragma unroll
  for (int n = 0; n < N; n++) {
    float x = v[n];
#pragma unroll
    for (int o = 32; o > 0; o >>= 1) x += __shfl_down(x, o);
    if (lane == 0) s[wv][n] = x;
  }
  __syncthreads();
#pragma unroll
  for (int n = 0; n < N; n++) v[n] = s[0][n] + s[1][n] + s[2][n] + s[3][n];
}

__global__ __launch_bounds__(256) void k_head(
    const float* __restrict__ hb, const float* __restrict__ mxb,
    const float* __restrict__ bp_src, const float* __restrict__ bp_tgt,
    const float* __restrict__ dist_bias, const float* __restrict__ plane_p,
    const float* __restrict__ plane_a, const int* __restrict__ alignment,
    float* __restrict__ outp)
{
  const int b = blockIdx.x;
  const int t = threadIdx.x;
  const int arow = 512 + alignment[b];
  float hs[2], htg[2];
  hs[0] = hb[(size_t)b * 512 + t];      hs[1] = hb[(size_t)b * 512 + 256 + t];
  htg[0] = hb[(size_t)arow * 512 + t];  htg[1] = hb[(size_t)arow * 512 + 256 + t];
  const float mxs = mxb[(size_t)b * 512 + t];
  const float mxt = mxb[(size_t)b * 512 + 256 + t];
  const float bps = bp_src[t], bpt = bp_tgt[t], db = dist_bias[t];
  const float pp0 = plane_p[t], pp1 = plane_p[256 + t];
  const float pa0 = plane_a[t], pa1 = plane_a[256 + t];

  float rA[5] = {0, 0, 0, 0, 0};
#pragma unroll
  for (int e = 0; e < 2; e++) {
    rA[0] += hs[e] * hs[e]; rA[1] += htg[e] * htg[e]; rA[2] += hs[e] * htg[e];
  }
  rA[3] = mxs * mxs; rA[4] = mxt * mxt;
  block_reduce<5>(rA);
  const float shs = rA[0], sht = rA[1], dot_st = rA[2];
  const float xns = sqrtf(fmaxf(shs, EPSF)), axns = artanh_c(xns);
  const float xnt = sqrtf(fmaxf(sht, EPSF)), axnt = artanh_c(xnt);
  const float ms = sqrtf(fmaxf(rA[3], EPSF)); const float ts = tanhf(ms / xns * axns);
  const float ss = (ms <= 1e-7f) ? 0.f : ts / ms; const float x2s = (ms <= 1e-7f) ? 0.f : ts * ts;
  const float mt = sqrtf(fmaxf(rA[4], EPSF)); const float tt = tanhf(mt / xnt * axnt);
  const float st = (mt <= 1e-7f) ? 0.f : tt / mt; const float x2t = (mt <= 1e-7f) ? 0.f : tt * tt;
  const float vs = ss * mxs, vt = st * mxt;

  float rB[5] = {bps * bps, vs * bps, bpt * bpt, vt * bpt, db * db};
  block_reduce<5>(rB);
  float ps, pt;
  {
    const float y2 = rB[0], xy = rB[1];
    const float iv = 1.f / fmaxf(1.f + 2.f * xy + x2s * y2, EPSF);
    ps = ((1.f + 2.f * xy + y2) * vs + (1.f - x2s) * bps) * iv;
  }
  {
    const float y2 = rB[2], xy = rB[3];
    const float iv = 1.f / fmaxf(1.f + 2.f * xy + x2t * y2, EPSF);
    pt = ((1.f + 2.f * xy + y2) * vt + (1.f - x2t) * bpt) * iv;
  }
  float rC[2] = {ps * ps, pt * pt};
  block_reduce<2>(rC);
  {
    const float n = sqrtf(fmaxf(rC[0], EPSF));
    if (n > 0.999f) ps *= 0.999f / n;
  }
  {
    const float n = sqrtf(fmaxf(rC[1], EPSF));
    if (n > 0.999f) pt *= 0.999f / n;
  }
  float df[2];
  {
    const float xy = -dot_st;
    const float iv = 1.f / fmaxf(1.f + 2.f * xy + shs * sht, EPSF);
    const float c1 = 1.f + 2.f * xy + sht, c2 = 1.f - shs;
#pragma unroll
    for (int e = 0; e < 2; e++) df[e] = (c1 * (-hs[e]) + c2 * htg[e]) * iv;
  }
  float rD[4] = {ps * ps, pt * pt, ps * pt, df[0] * df[0] + df[1] * df[1]};
  block_reduce<4>(rD);
  float pr;
  {
    const float x2 = rD[0], y2 = rD[1], xy = rD[2];
    const float iv = 1.f / fmaxf(1.f + 2.f * xy + x2 * y2, EPSF);
    pr = ((1.f + 2.f * xy + y2) * ps + (1.f - x2) * pt) * iv;
  }
  const float dn = sqrtf(fmaxf(rD[3], EPSF));
  const float dist = 2.f * artanh_c(dn);
  const float d2v = dist * dist;
  const float dbn = sqrtf(fmaxf(rB[4], EPSF));
  const float biasv = tanhf(d2v * artanh_c(dbn)) * db / dbn;

  float rE[3] = {pr * pr, biasv * biasv, pr * biasv};
  block_reduce<3>(rE);
  float pr2;
  {
    const float x2 = rE[0], y2 = rE[1], xy = rE[2];
    const float iv = 1.f / fmaxf(1.f + 2.f * xy + x2 * y2, EPSF);
    pr2 = ((1.f + 2.f * xy + y2) * pr + (1.f - x2) * biasv) * iv;
  }
  float rF[5] = {pp0 * pp0, pp0 * pr2, pp1 * pp1, pp1 * pr2, pr2 * pr2};
  block_reduce<5>(rF);
  float d0, d1;
  {
    const float x2 = rF[0], xy = -rF[1], y2 = rF[4];
    const float iv = 1.f / fmaxf(1.f + 2.f * xy + x2 * y2, EPSF);
    d0 = ((1.f + 2.f * xy + y2) * (-pp0) + (1.f - x2) * pr2) * iv;
  }
  {
    const float x2 = rF[2], xy = -rF[3], y2 = rF[4];
    const float iv = 1.f / fmaxf(1.f + 2.f * xy + x2 * y2, EPSF);
    d1 = ((1.f + 2.f * xy + y2) * (-pp1) + (1.f - x2) * pr2) * iv;
  }
  float rG[6] = {d0 * d0, d0 * pa0, pa0 * pa0, d1 * d1, d1 * pa1, pa1 * pa1};
  block_reduce<6>(rG);
  if (t == 0) {
    const float an0 = sqrtf(fmaxf(rG[2], EPSF));
    const float an1 = sqrtf(fmaxf(rG[5], EPSF));
    outp[b * 2 + 0] = asinhf(2.f * rG[1] / fmaxf((1.f - rG[0]) * an0, EPSF));
    outp[b * 2 + 1] = asinhf(2.f * rG[4] / fmaxf((1.f - rG[3]) * an1, EPSF));
  }
}

// ---------- launch ----------
extern "C" void kernel_launch(void* const* d_in, const int* in_sizes, int n_in,
                              void* d_out, int out_size, void* d_ws, size_t ws_size,
                              hipStream_t stream) {
  const float* emb       = (const float*)d_in[0];
  const float* w_ih_src  = (const float*)d_in[1];
  const float* w_hh_src  = (const float*)d_in[2];
  const float* b_src     = (const float*)d_in[3];
  const float* w_ih_tgt  = (const float*)d_in[4];
  const float* w_hh_tgt  = (const float*)d_in[5];
  const float* b_tgt     = (const float*)d_in[6];
  const float* wp_src    = (const float*)d_in[7];
  const float* bp_src    = (const float*)d_in[8];
  const float* wp_tgt    = (const float*)d_in[9];
  const float* bp_tgt    = (const float*)d_in[10];
  const float* dist_bias = (const float*)d_in[11];
  const float* plane_p   = (const float*)d_in[12];
  const float* plane_a   = (const float*)d_in[13];
  const int* src_t       = (const int*)d_in[14];
  const int* tgt_t       = (const int*)d_in[15];
  const int* alignment   = (const int*)d_in[16];
  float* outp            = (float*)d_out;

  char* wsb = (char*)d_ws;
  float* yws   = (float*)(wsb + 0);          // 64 x [16][2560] f32 = 10.5 MB
  float* htmws = (float*)(wsb + 10485760);   // 64 x [16][512]  f32 = 2 MB
  float* hbuf  = (float*)(wsb + 12582912);   // [1024][512] f32 = 2 MB
  float* mxb   = (float*)(wsb + 14680064);   // [512][512]  f32 = 1 MB
  bf16*  W0h   = (bf16*)(wsb + 15728640);    // 1835008 bf16 = 3.67 MB
  bf16*  W1h   = (bf16*)(wsb + 19398656);    // 524288 bf16 = 1.05 MB; end ~20.4 MB

  k_wconv<<<9216, 256, 0, stream>>>(w_ih_src, w_hh_src, w_ih_tgt, w_hh_tgt,
                                    W0h, W1h);
  k_rnn<<<64, 512, 0, stream>>>(emb, src_t, tgt_t, b_src, b_tgt,
                                W0h, W1h, yws, htmws, hbuf);
  gemm_k<<<dim3(8, 8), 256, 0, stream>>>(hbuf, wp_src, wp_tgt, alignment, mxb);
  k_head<<<512, 256, 0, stream>>>(hbuf, mxb, bp_src, bp_tgt, dist_bias,
                                  plane_p, plane_a, alignment, outp);
}